// Round 6
// baseline (1505.188 us; speedup 1.0000x reference)
//
#include <hip/hip_runtime.h>
#include <math.h>

// HELPv3: 8-layer bipartite GAT + pooling + 2 softmax heads.
// R13 (= R12 + missing gemmb2_k restored): softmax hoisted out of attn2_k.
//      elsm_k (per layer): edge-parallel logits (rec carries dst in .w) ->
//      coalesced lgsrc {lg,src}, thread-per-node max/sum from LDS -> ms {m,1/s}.
//      attn2_k loses shfl reductions, rec load, a_s scatter, lrelu.
//      lgsrc/ms overlay the dead phist region (no extra workspace).
// Carried: readlane-scalarized gather, rcp/__expf/cvt_pk trims, 16B edge
//          records, global_load_lds GEMM staging, privatized histogram.

#define NNODE 50000
#define EDG   500000
#define DIM   256
#define LAY   8
#define BB    512
#define CC    117
#define EMBD  544
#define SCB   49          // scan blocks: 49*1024 >= 50000
#define HW    16384       // hist window (nodes), 64KB LDS
#define HC    16          // hist chunk count (private copies)
#define HNW   4           // windows: 4*16384 >= 50000
#define LDSE  8192        // elsm LDS logit slots (32KB)

typedef short bf16x8 __attribute__((ext_vector_type(8)));
typedef float f32x4  __attribute__((ext_vector_type(4)));

static __device__ __forceinline__ float lrelu(float x){ return x >= 0.f ? x : 0.2f*x; }
static __device__ __forceinline__ unsigned short f2b(float f){
  unsigned int u = __float_as_uint(f);
  unsigned int r = (u + 0x7fffu + ((u >> 16) & 1u)) >> 16;   // RNE
  return (unsigned short)r;
}
static __device__ __forceinline__ float b2f(unsigned short u){
  return __uint_as_float(((unsigned int)u) << 16);
}
static __device__ __forceinline__ float blo(unsigned int u){
  return __uint_as_float(u << 16);
}
static __device__ __forceinline__ float bhi(unsigned int u){
  return __uint_as_float(u & 0xffff0000u);
}
// packed RNE f32->bf16x2 (same rounding as f2b, 1 instr instead of ~8)
static __device__ __forceinline__ unsigned cvtpk(float lo, float hi){
  unsigned r;
  asm("v_cvt_pk_bf16_f32 %0, %1, %2" : "=v"(r) : "v"(lo), "v"(hi));
  return r;
}
// wave-uniform broadcasts (SGPR result; no ds_bpermute)
static __device__ __forceinline__ float rdlane_f(float v, int id){
  return __uint_as_float(__builtin_amdgcn_readlane(__float_as_uint(v), id));
}
static __device__ __forceinline__ int rdlane_i(int v, int id){
  return __builtin_amdgcn_readlane(v, id);
}

static __device__ __forceinline__ void gload_lds16(const void* g, void* l){
  __builtin_amdgcn_global_load_lds((const __attribute__((address_space(1))) void*)g,
                                   (__attribute__((address_space(3))) void*)l,
                                   16, 0, 0);
}

// v[k] = sum_j W[k*256+j]*a[j] for 32 (l,rel,which) combos; one wave per output k
__global__ void vcompute_k(const float* __restrict__ Wsho, const float* __restrict__ Wdho,
                           const float* __restrict__ asho, const float* __restrict__ adho,
                           const float* __restrict__ Wsoh, const float* __restrict__ Wdoh,
                           const float* __restrict__ asoh, const float* __restrict__ adoh,
                           float* __restrict__ vbuf){
  int gid = blockIdx.x*blockDim.x + threadIdx.x;
  int wv = gid >> 6, lane = gid & 63;
  if (wv >= 32*DIM) return;
  int p = wv >> 8, k = wv & 255;
  int which = p & 1, rel = (p>>1)&1, l = p>>2;
  const float* W; const float* a;
  if (rel==0){ W = which? Wdho : Wsho; a = which? adho : asho; }
  else       { W = which? Wdoh : Wsoh; a = which? adoh : asoh; }
  W += (size_t)l*DIM*DIM; a += (size_t)l*DIM;
  const float4* w4 = (const float4*)(W + (size_t)k*DIM);
  const float4* a4 = (const float4*)a;
  float4 wv4 = w4[lane], av4 = a4[lane];
  float s = wv4.x*av4.x + wv4.y*av4.y + wv4.z*av4.z + wv4.w*av4.w;
  for (int off=32; off; off>>=1) s += __shfl_xor(s, off);
  if (lane==0) vbuf[(size_t)p*DIM + k] = s;
}

__global__ void wecompute_k(const float* __restrict__ Weho, const float* __restrict__ aeho,
                            const float* __restrict__ Weoh, const float* __restrict__ aeoh,
                            float* __restrict__ webuf){
  int blk = blockIdx.x;            // l*2 + rel
  int rel = blk & 1, l = blk >> 1;
  const float* We = rel? Weoh : Weho;
  const float* ae = rel? aeoh : aeho;
  int lane = threadIdx.x;          // 64
  const float4* w0 = (const float4*)(We + (size_t)l*2*DIM);
  const float4* w1 = (const float4*)(We + (size_t)l*2*DIM + DIM);
  const float4* a4 = (const float4*)(ae + (size_t)l*DIM);
  float4 av = a4[lane], x0 = w0[lane], x1 = w1[lane];
  float s0 = x0.x*av.x + x0.y*av.y + x0.z*av.z + x0.w*av.w;
  float s1 = x1.x*av.x + x1.y*av.y + x1.z*av.z + x1.w*av.w;
  for (int off=32; off; off>>=1){ s0 += __shfl_xor(s0, off); s1 += __shfl_xor(s1, off); }
  if (lane==0){ webuf[blk*2] = s0; webuf[blk*2+1] = s1; }
}

// privatized histogram: block (x=chunk, y=window, z=array) counts its chunk's
// in-window keys in LDS, writes private copy (coalesced, no atomics).
// phist[((z*HNW + y)*HC + x)*HW + off]
__global__ void histp_k(const int* __restrict__ ei_ho, const int* __restrict__ ei_oh,
                        int* __restrict__ phist){
  __shared__ int h[HW];
  int x = blockIdx.x, y = blockIdx.y, z = blockIdx.z, t = threadIdx.x;
  for (int i=t; i<HW; i+=256) h[i] = 0;
  __syncthreads();
  const int* keys = (z==0)? (ei_ho + EDG) : (z==1)? (ei_oh + EDG) : ei_ho;
  int lo = y << 14;
  int e0 = x * (EDG/HC), e1 = e0 + (EDG/HC);
  for (int e = e0 + t; e < e1; e += 256){
    int k = keys[e] - lo;
    if ((unsigned)k < (unsigned)HW) atomicAdd(&h[k], 1);
  }
  __syncthreads();
  int* dst = phist + (size_t)(((z*HNW + y)*HC + x))*HW;
  for (int i=t; i<HW; i+=256) dst[i] = h[i];
}

static __device__ __forceinline__ int4 phist_sum4(const int* __restrict__ phist,
                                                  int z, int idx){
  int win = idx >> 14, off = idx & (HW-1);
  const int* base = phist + (size_t)((z*HNW + win)*HC)*HW + off;
  int4 s = make_int4(0,0,0,0);
  #pragma unroll
  for (int c=0;c<HC;c++){
    int4 v = *(const int4*)(base + (size_t)c*HW);
    s.x += v.x; s.y += v.y; s.z += v.z; s.w += v.w;
  }
  return s;
}

// Phase A: per-block sums (grid SCB x 3, 256 thr, 4 elem/thr)
__global__ void scanA_k(const int* __restrict__ phist, int* __restrict__ bsum){
  __shared__ int sh[256];
  int y = blockIdx.y, b = blockIdx.x, t = threadIdx.x;
  int idx = b*1024 + t*4;
  int s = 0;
  if (idx + 3 < NNODE){
    int4 v = phist_sum4(phist, y, idx);
    s = v.x + v.y + v.z + v.w;
  } else {
    for (int j=0;j<4;j++) if (idx+j < NNODE){
      int win = (idx+j) >> 14, off = (idx+j) & (HW-1);
      for (int c=0;c<HC;c++) s += phist[(size_t)((y*HNW+win)*HC+c)*HW + off];
    }
  }
  sh[t] = s; __syncthreads();
  for (int off=128; off; off>>=1){ if (t<off) sh[t] += sh[t+off]; __syncthreads(); }
  if (t==0) bsum[y*SCB + b] = sh[0];
}

__global__ void scanB_k(int* __restrict__ bsum, int* __restrict__ boff,
                        int* __restrict__ rp0, int* __restrict__ rp1, int* __restrict__ rp2){
  int t = threadIdx.x;
  if (t >= 3) return;
  int run = 0;
  for (int i=0;i<SCB;i++){ boff[t*SCB+i] = run; run += bsum[t*SCB+i]; }
  int* rp = (t==0)? rp0 : (t==1)? rp1 : rp2;
  rp[NNODE] = run;
}

__global__ void scanC_k(const int* __restrict__ phist, const int* __restrict__ boff,
                        int* __restrict__ rp0, int* __restrict__ rp1, int* __restrict__ rp2){
  __shared__ int sh[256];
  int y = blockIdx.y, b = blockIdx.x, t = threadIdx.x;
  int* rp = (y==0)? rp0 : (y==1)? rp1 : rp2;
  int idx = b*1024 + t*4;
  int c[4] = {0,0,0,0};
  if (idx + 3 < NNODE){
    int4 v = phist_sum4(phist, y, idx);
    c[0]=v.x; c[1]=v.y; c[2]=v.z; c[3]=v.w;
  } else {
    for (int j=0;j<4;j++) if (idx+j < NNODE){
      int win = (idx+j) >> 14, off = (idx+j) & (HW-1);
      for (int cc=0;cc<HC;cc++) c[j] += phist[(size_t)((y*HNW+win)*HC+cc)*HW + off];
    }
  }
  int mysum = c[0]+c[1]+c[2]+c[3];
  sh[t] = mysum; __syncthreads();
  for (int off=1; off<256; off<<=1){
    int v = (t>=off) ? sh[t-off] : 0;
    __syncthreads();
    sh[t] += v;
    __syncthreads();
  }
  int base = boff[y*SCB + b] + (sh[t] - mysum);
  int run = 0;
  for (int j=0;j<4;j++){
    if (idx+j < NNODE) rp[idx+j] = base + run;
    run += c[j];
  }
}

// fused scatters: y=0 dst(ho), y=1 dst(oh), y=2 src(ho)
// 16B records {src_as_float, ea.x, ea.y, dst_as_float} -> 1 dirty line/edge
__global__ void scatter3_k(const int* __restrict__ ei_ho, const int* __restrict__ ei_oh,
                           const float* __restrict__ ea_ho, const float* __restrict__ ea_oh,
                           const int* __restrict__ rp0, const int* __restrict__ rp1,
                           const int* __restrict__ rp2, int* __restrict__ cur,
                           float4* __restrict__ rec0, float4* __restrict__ rec1,
                           float2* __restrict__ eap2){
  int e = blockIdx.x*blockDim.x + threadIdx.x;
  if (e >= EDG) return;
  int y = blockIdx.y;
  if (y == 0){
    int d = ei_ho[EDG + e];
    int pos = rp0[d] + atomicAdd(&cur[d], 1);
    rec0[pos] = make_float4(__int_as_float(ei_ho[e]), ea_ho[2*e], ea_ho[2*e+1],
                            __int_as_float(d));
  } else if (y == 1){
    int d = ei_oh[EDG + e];
    int pos = rp1[d] + atomicAdd(&cur[NNODE + d], 1);
    rec1[pos] = make_float4(__int_as_float(ei_oh[e]), ea_oh[2*e], ea_oh[2*e+1],
                            __int_as_float(d));
  } else {
    int s = ei_ho[e];
    int pos = rp2[s] + atomicAdd(&cur[2*NNODE + s], 1);
    eap2[pos] = make_float2(ea_ho[2*e], ea_ho[2*e+1]);
  }
}

// fused fp32->bf16 convert + layer-0 a_s/a_d dots. One wave per row; z = h/o.
__global__ void xcdg_k(const float* __restrict__ xh_in, const float* __restrict__ xo_in,
                       unsigned short* __restrict__ xhb, unsigned short* __restrict__ xob,
                       const float* __restrict__ vbuf, float* __restrict__ aset){
  int gid = blockIdx.x*blockDim.x + threadIdx.x;
  int w = gid >> 6, lane = gid & 63;
  if (w >= NNODE) return;
  int z = blockIdx.y;
  const float* X = z? xo_in : xh_in;
  unsigned short* O = z? xob : xhb;
  const float* v1 = vbuf + (size_t)(z? 2:0)*DIM;   // as (src-role)
  const float* v2 = vbuf + (size_t)(z? 1:3)*DIM;   // ad (dst-role)
  float* o1 = aset + (size_t)(z? 2:0)*NNODE;
  float* o2 = aset + (size_t)(z? 1:3)*NNODE;
  float4 xv = ((const float4*)(X + (size_t)w*DIM))[lane];
  uint2 ob; ob.x = cvtpk(xv.x, xv.y); ob.y = cvtpk(xv.z, xv.w);
  ((uint2*)O)[(size_t)w*64 + lane] = ob;
  float4 a = ((const float4*)v1)[lane];
  float4 b = ((const float4*)v2)[lane];
  float s1 = xv.x*a.x + xv.y*a.y + xv.z*a.z + xv.w*a.w;
  float s2 = xv.x*b.x + xv.y*b.y + xv.z*b.z + xv.w*b.w;
  for (int off=32; off; off>>=1){ s1 += __shfl_xor(s1, off); s2 += __shfl_xor(s2, off); }
  if (lane==0){ o1[w] = s1; o2[w] = s2; }
}

// Wt[rel][l][n][k] = bf16(W[rel][l][k][n])
__global__ void wtconv_k(const float* __restrict__ Who, const float* __restrict__ Woh,
                         unsigned short* __restrict__ Wt){
  int gid = blockIdx.x*blockDim.x + threadIdx.x;   // < 1048576
  int rel = gid >> 19;
  int rem = gid & ((1<<19)-1);
  int l = rem >> 16;
  int idx = rem & 65535;
  int n = idx >> 8, k = idx & 255;
  const float* W = rel ? Woh : Who;
  Wt[gid] = f2b(W[(size_t)l*65536 + (size_t)k*256 + n]);
}

// fused GEMM pair: z=0: H0=xh@Wl_ho; z=1: H1=xo@Wl_oh. 128x128 tile, 4 waves.
// Staging via global_load_lds width=16: LDS dst linear (wave base + lane*16),
// global src pre-permuted so chunk c holds (row,sq) with
//   row = ((c>>6)<<4)|(c&15), sq = (c>>4)&3  (bijection matching frag reads).
// M-overflow rows clamp src to row M-1; garbage confined to masked output rows.
__global__ __launch_bounds__(256) void gemmb2_k(const unsigned short* __restrict__ A0,
                                                const unsigned short* __restrict__ A1,
                                                const unsigned short* __restrict__ B0,
                                                const unsigned short* __restrict__ B1,
                                                unsigned short* __restrict__ H0,
                                                unsigned short* __restrict__ H1, int M){
  __shared__ __align__(16) unsigned short As[4096];
  __shared__ __align__(16) unsigned short Bs[4096];
  int z = blockIdx.z;
  const unsigned short* A  = z? A1 : A0;
  const unsigned short* Bt = z? B1 : B0;
  unsigned short* H        = z? H1 : H0;
  int tid = threadIdx.x;
  int col0 = blockIdx.x * 128;
  int row0 = blockIdx.y * 128;
  int w = tid >> 6, lane = tid & 63;
  int q = lane >> 4, ml = lane & 15;
  f32x4 acc[2][8];
  #pragma unroll
  for (int i=0;i<2;i++)
    #pragma unroll
    for (int j=0;j<8;j++) acc[i][j] = (f32x4){0.f,0.f,0.f,0.f};

  // per-lane permuted global sources for the 2 staging issues (p=0,1)
  const unsigned short* srcA[2];
  const unsigned short* srcB[2];
  #pragma unroll
  for (int p=0;p<2;p++){
    int c = p*256 + w*64 + lane;             // linear chunk index in LDS
    int row = ((c>>6)<<4) | (c&15);
    int sq  = (c>>4)&3;
    int gr = row0 + row; if (gr >= M) gr = M-1;   // clamp; masked at store
    srcA[p] = A  + (size_t)gr*256 + sq*8;
    srcB[p] = Bt + (size_t)(col0 + row)*256 + sq*8;
  }

  for (int k0 = 0; k0 < 256; k0 += 32){
    #pragma unroll
    for (int p = 0; p < 2; ++p){
      gload_lds16(srcA[p], &As[(size_t)(p*256 + w*64)*8]);
      gload_lds16(srcB[p], &Bs[(size_t)(p*256 + w*64)*8]);
      srcA[p] += 32; srcB[p] += 32;
    }
    __syncthreads();   // compiler emits vmcnt(0) drain before barrier
    bf16x8 a0 = *(const bf16x8*)&As[(((2*w+0)*4 + q)*16 + ml)*8];
    bf16x8 a1 = *(const bf16x8*)&As[(((2*w+1)*4 + q)*16 + ml)*8];
    #pragma unroll
    for (int nf = 0; nf < 8; ++nf){
      bf16x8 b = *(const bf16x8*)&Bs[((nf*4 + q)*16 + ml)*8];
      acc[0][nf] = __builtin_amdgcn_mfma_f32_16x16x32_bf16(a0, b, acc[0][nf], 0,0,0);
      acc[1][nf] = __builtin_amdgcn_mfma_f32_16x16x32_bf16(a1, b, acc[1][nf], 0,0,0);
    }
    __syncthreads();
  }
  #pragma unroll
  for (int mf = 0; mf < 2; ++mf){
    #pragma unroll
    for (int r = 0; r < 4; ++r){
      int gr = row0 + 32*w + 16*mf + q*4 + r;
      if (gr < M){
        #pragma unroll
        for (int nf = 0; nf < 8; ++nf)
          H[(size_t)gr*256 + col0 + nf*16 + ml] = f2b(acc[mf][nf][r]);
      }
    }
  }
}

// per-layer edge logits + node softmax stats. Block = 128 nodes, 256 threads.
// Phase 1 (edge-parallel): lg = lrelu(a_s[src]+a_d[dst]+ea.w0+ea.w1), write
// coalesced lgsrc[e]={lg,src}, mirror lg to LDS. Phase 2 (thread-per-node):
// m = max(lg), s = sum exp(lg-m) -> ms[n] = {m, rcp(s)}.
__global__ __launch_bounds__(256) void elsm_k(
    const int* __restrict__ rp0, const float4* __restrict__ rec0,
    const int* __restrict__ rp1, const float4* __restrict__ rec1,
    const float* __restrict__ cur_a, const float* __restrict__ wepl,
    uint2* __restrict__ lgsrc0, uint2* __restrict__ lgsrc1,
    float2* __restrict__ ms0, float2* __restrict__ ms1){
  __shared__ float lgs[LDSE];
  int rel = blockIdx.y;
  const int* rp = rel? rp1 : rp0;
  const float4* rec = rel? rec1 : rec0;
  const float* a_s = cur_a + (size_t)(rel? 2:0)*NNODE;
  const float* a_d = cur_a + (size_t)(rel? 3:1)*NNODE;
  float w0 = wepl[rel? 2:0], w1 = wepl[rel? 3:1];
  uint2* lgsrc = rel? lgsrc1 : lgsrc0;
  float2* ms = rel? ms1 : ms0;
  int n0 = blockIdx.x * 128;
  int n1 = n0 + 128; if (n1 > NNODE) n1 = NNODE;
  int t = threadIdx.x;
  int e0 = rp[n0], e1 = rp[n1];
  bool fit = (e1 - e0) <= LDSE;
  for (int e = e0 + t; e < e1; e += 256){
    float4 r = rec[e];
    int src = __float_as_int(r.x);
    int dst = __float_as_int(r.w);
    float lg = lrelu(a_s[src] + a_d[dst] + r.y*w0 + r.z*w1);
    lgsrc[e] = make_uint2(__float_as_uint(lg), (unsigned)src);
    if (fit) lgs[e - e0] = lg;
  }
  __syncthreads();
  if (t < 128){
    int n = n0 + t;
    if (n < NNODE){
      int st = rp[n], en = rp[n+1];
      float m = -INFINITY, s = 0.f;
      if (fit){
        for (int p=st;p<en;p++) m = fmaxf(m, lgs[p-e0]);
        for (int p=st;p<en;p++) s += __expf(lgs[p-e0] - m);
      } else {
        for (int p=st;p<en;p++) m = fmaxf(m, __uint_as_float(lgsrc[p].x));
        for (int p=st;p<en;p++) s += __expf(__uint_as_float(lgsrc[p].x) - m);
      }
      ms[n] = make_float2(m, __builtin_amdgcn_rcpf(s));
    }
  }
}

// fused attn pair (y = relation). One wave per dst node. Pure gather now:
// wgt = exp(lg - m)*inv from precomputed lgsrc/ms; readlane-scalarized loop.
__global__ void attn2_k(const int* __restrict__ rp0, const uint2* __restrict__ lgsrc0,
                        const int* __restrict__ rp1, const uint2* __restrict__ lgsrc1,
                        const float2* __restrict__ ms0, const float2* __restrict__ ms1,
                        float* __restrict__ nxt_a,
                        const unsigned short* __restrict__ hs0,
                        const unsigned short* __restrict__ hs1,
                        const float* __restrict__ bias0, const float* __restrict__ bias1,
                        const unsigned short* __restrict__ xprev0,
                        const unsigned short* __restrict__ xprev1,
                        unsigned short* __restrict__ xnext0,
                        unsigned short* __restrict__ xnext1,
                        const float* __restrict__ vbl,
                        int hasRes, int doNext){
  int gid = blockIdx.x*blockDim.x + threadIdx.x;
  int w = gid >> 6, lane = gid & 63;
  if (w >= NNODE) return;
  int rel = blockIdx.y;
  const int* rowptr = rel? rp1 : rp0;
  const uint2* lgsrc = rel? lgsrc1 : lgsrc0;
  const float2* msb = rel? ms1 : ms0;
  const unsigned short* hs = rel? hs1 : hs0;
  const float* bias = rel? bias1 : bias0;
  const unsigned short* xprev = rel? xprev1 : xprev0;
  unsigned short* xnext = rel? xnext1 : xnext0;

  int st = rowptr[w], en = rowptr[w+1];
  int deg = en - st;
  float2 msv = msb[w];

  // hoisted independent epilogue loads (overlap their latency with the gather)
  float4 bv = ((const float4*)bias)[lane];
  uint2 rres = ((const uint2*)xprev)[(size_t)w*64 + lane];
  float4 va = ((const float4*)(vbl + (size_t)(rel? 0:2)*DIM))[lane];
  float4 vc = ((const float4*)(vbl + (size_t)(rel? 3:1)*DIM))[lane];

  float ax=0.f, ay=0.f, az=0.f, aw=0.f;
  if (deg > 0 && deg <= 64){
    int sreg = 0; float wgt = 0.f;
    if (lane < deg){
      uint2 ls = lgsrc[st + lane];
      sreg = (int)ls.y;
      wgt = __expf(__uint_as_float(ls.x) - msv.x) * msv.y;
    }
    int i = 0;
    for (; i + 7 < deg; i += 8){
      float wi[8]; const uint2* rp[8];
      #pragma unroll
      for (int j=0;j<8;j++){
        wi[j] = rdlane_f(wgt, i+j);
        rp[j] = (const uint2*)(hs + (size_t)rdlane_i(sreg, i+j)*DIM);
      }
      uint2 hv[8];
      #pragma unroll
      for (int j=0;j<8;j++) hv[j] = rp[j][lane];
      #pragma unroll
      for (int j=0;j<8;j++){
        ax += wi[j]*blo(hv[j].x); ay += wi[j]*bhi(hv[j].x);
        az += wi[j]*blo(hv[j].y); aw += wi[j]*bhi(hv[j].y);
      }
    }
    for (; i + 3 < deg; i += 4){
      float wi[4]; const uint2* rp[4];
      #pragma unroll
      for (int j=0;j<4;j++){
        wi[j] = rdlane_f(wgt, i+j);
        rp[j] = (const uint2*)(hs + (size_t)rdlane_i(sreg, i+j)*DIM);
      }
      uint2 hv[4];
      #pragma unroll
      for (int j=0;j<4;j++) hv[j] = rp[j][lane];
      #pragma unroll
      for (int j=0;j<4;j++){
        ax += wi[j]*blo(hv[j].x); ay += wi[j]*bhi(hv[j].x);
        az += wi[j]*blo(hv[j].y); aw += wi[j]*bhi(hv[j].y);
      }
    }
    for (; i < deg; ++i){
      float wi = rdlane_f(wgt, i);
      const uint2* rp = (const uint2*)(hs + (size_t)rdlane_i(sreg, i)*DIM);
      uint2 hv = rp[lane];
      ax += wi*blo(hv.x); ay += wi*bhi(hv.x);
      az += wi*blo(hv.y); aw += wi*bhi(hv.y);
    }
  } else if (deg > 64){
    for (int p = st; p < en; ++p){
      uint2 ls = lgsrc[p];
      float wgt = __expf(__uint_as_float(ls.x) - msv.x) * msv.y;
      const uint2* rp = (const uint2*)(hs + (size_t)ls.y*DIM);
      uint2 hv = rp[lane];
      ax += wgt*blo(hv.x); ay += wgt*bhi(hv.x);
      az += wgt*blo(hv.y); aw += wgt*bhi(hv.y);
    }
  }

  float resw = hasRes ? 1.f : 0.f;
  float4 o;
  o.x = fmaxf(ax + bv.x, 0.f) + resw*blo(rres.x);
  o.y = fmaxf(ay + bv.y, 0.f) + resw*bhi(rres.x);
  o.z = fmaxf(az + bv.z, 0.f) + resw*blo(rres.y);
  o.w = fmaxf(aw + bv.w, 0.f) + resw*bhi(rres.y);
  uint2 ob; ob.x = cvtpk(o.x, o.y); ob.y = cvtpk(o.z, o.w);
  ((uint2*)xnext)[(size_t)w*64 + lane] = ob;
  if (doNext){
    float s1 = o.x*va.x + o.y*va.y + o.z*va.z + o.w*va.w;
    float s2 = o.x*vc.x + o.y*vc.y + o.z*vc.z + o.w*vc.w;
    for (int off=32; off; off>>=1){ s1 += __shfl_xor(s1, off); s2 += __shfl_xor(s2, off); }
    if (lane==0){
      float* asn = nxt_a + (size_t)(rel? 0:2)*NNODE;
      float* adn = nxt_a + (size_t)(rel? 3:1)*NNODE;
      asn[w] = s1; adn[w] = s2;
    }
  }
}

__device__ __forceinline__ int lowerb(const int* a, int n, int v){
  int lo=0, hi=n;
  while (lo < hi){ int m = (lo+hi)>>1; if (a[m] < v) lo = m+1; else hi = m; }
  return lo;
}

// bf16 x pooling pair (y = h/o): block per batch, coalesced column sums
__global__ void pool2_k(const unsigned short* __restrict__ xh, const unsigned short* __restrict__ xo,
                        const int* __restrict__ hbatch, const int* __restrict__ obatch,
                        float* __restrict__ hpool, float* __restrict__ opool){
  int z = blockIdx.y;
  const unsigned short* x = z? xo : xh;
  const int* batch = z? obatch : hbatch;
  float* out = z? opool : hpool;
  int b = blockIdx.x, t = threadIdx.x; // 256
  int st = lowerb(batch, NNODE, b), en = lowerb(batch, NNODE, b+1);
  float s = 0.f;
  for (int i=st;i<en;i++) s += b2f(x[(size_t)i*DIM + t]);
  out[(size_t)b*DIM + t] = s / fmaxf((float)(en - st), 1.f);
}

// fused edge-MLP pool: hbatch sorted + src-CSR => batch b's edges contiguous.
__global__ void epool_k(const int* __restrict__ rp_src, const int* __restrict__ hbatch,
                        const float2* __restrict__ eaperm, const float* __restrict__ Wem,
                        const float* __restrict__ bem, float* __restrict__ epool){
  __shared__ float ps[8][33];
  int b = blockIdx.x, t = threadIdx.x; // 256
  int j = t & 31, g = t >> 5;
  int nst = lowerb(hbatch, NNODE, b), nen = lowerb(hbatch, NNODE, b+1);
  int est = rp_src[nst], een = rp_src[nen];
  float w0 = Wem[j], w1 = Wem[32+j], bb = bem[j];
  float s = 0.f;
  for (int p = est + g; p < een; p += 8){
    float2 e = eaperm[p];
    s += fmaxf(e.x*w0 + e.y*w1 + bb, 0.f);
  }
  ps[g][j] = s; __syncthreads();
  if (g == 0){
    float tot = 0.f;
    #pragma unroll
    for (int gg=0; gg<8; gg++) tot += ps[gg][j];
    epool[(size_t)b*32 + j] = tot / fmaxf((float)(een - est), 1.f);
  }
}

__global__ void head_k(const float* __restrict__ hpool, const float* __restrict__ opool,
                       const float* __restrict__ epool,
                       const float* __restrict__ Wp1, const float* __restrict__ bp1,
                       const float* __restrict__ Wp2, const float* __restrict__ bp2,
                       float* __restrict__ out){
  __shared__ float emb[EMBD];
  __shared__ float red[256];
  int b = blockIdx.x, t = threadIdx.x; // 256
  emb[t] = hpool[(size_t)b*DIM + t];
  emb[DIM + t] = opool[(size_t)b*DIM + t];
  if (t < 32) emb[2*DIM + t] = epool[(size_t)b*32 + t];
  __syncthreads();
  for (int h = 0; h < 2; ++h){
    const float* Wp = h? Wp2 : Wp1;
    const float* bp = h? bp2 : bp1;
    float logit = -INFINITY;
    if (t < CC){
      float s = bp[t];
      for (int k=0;k<EMBD;k++) s += emb[k]*Wp[(size_t)k*CC + t];
      logit = s;
    }
    red[t] = logit; __syncthreads();
    for (int off=128; off; off>>=1){ if (t<off) red[t] = fmaxf(red[t], red[t+off]); __syncthreads(); }
    float mx = red[0]; __syncthreads();
    float ex = (t < CC) ? expf(logit - mx) : 0.f;
    red[t] = ex; __syncthreads();
    for (int off=128; off; off>>=1){ if (t<off) red[t] += red[t+off]; __syncthreads(); }
    float sm = red[0]; __syncthreads();
    if (t < CC) out[((size_t)b*2 + h)*CC + t] = ex / sm;
  }
}

extern "C" void kernel_launch(void* const* d_in, const int* in_sizes, int n_in,
                              void* d_out, int out_size, void* d_ws, size_t ws_size,
                              hipStream_t stream) {
  (void)in_sizes; (void)n_in; (void)out_size; (void)ws_size;
  const float* xh_in   = (const float*)d_in[0];
  const float* xo_in   = (const float*)d_in[1];
  const int*   ei_ho   = (const int*)d_in[2];
  const int*   ei_oh   = (const int*)d_in[3];
  const float* ea_ho   = (const float*)d_in[4];
  const float* ea_oh   = (const float*)d_in[5];
  const int*   hbatch  = (const int*)d_in[6];
  const int*   obatch  = (const int*)d_in[7];
  const float* Wsrc_ho = (const float*)d_in[8];
  const float* Wdst_ho = (const float*)d_in[9];
  const float* asrc_ho = (const float*)d_in[10];
  const float* adst_ho = (const float*)d_in[11];
  const float* Wedge_ho= (const float*)d_in[12];
  const float* aedge_ho= (const float*)d_in[13];
  const float* bias_ho = (const float*)d_in[14];
  const float* Wsrc_oh = (const float*)d_in[15];
  const float* Wdst_oh = (const float*)d_in[16];
  const float* asrc_oh = (const float*)d_in[17];
  const float* adst_oh = (const float*)d_in[18];
  const float* Wedge_oh= (const float*)d_in[19];
  const float* aedge_oh= (const float*)d_in[20];
  const float* bias_oh = (const float*)d_in[21];
  const float* W_emlp  = (const float*)d_in[22];
  const float* b_emlp  = (const float*)d_in[23];
  const float* W_p1    = (const float*)d_in[24];
  const float* b_p1    = (const float*)d_in[25];
  const float* W_p2    = (const float*)d_in[26];
  const float* b_p2    = (const float*)d_in[27];
  float* out = (float*)d_out;

  size_t ND = (size_t)NNODE*DIM;
  float* f = (float*)d_ws;
  float* aset0 = f;                        // [asho adho asoh adoh] set 0
  float* aset1 = aset0 + 4*NNODE;          // set 1
  float* vbuf  = aset1 + 4*NNODE;          // 32*256
  float* webuf = vbuf + 32*DIM;            // 32
  float* hpool = webuf + 32;               // BB*DIM
  float* opool = hpool + (size_t)BB*DIM;
  float* epool = opool + (size_t)BB*DIM;   // BB*32
  float4* rec_ho  = (float4*)(epool + (size_t)BB*32);   // E float4 records
  float4* rec_oh  = rec_ho + EDG;
  float2* eap_src = (float2*)(rec_oh + EDG);            // E float2
  unsigned short* xhb0 = (unsigned short*)(eap_src + EDG);  // 6 x ND bf16
  unsigned short* xhb1 = xhb0 + ND;        // also holds bf16(xh_in) initially
  unsigned short* xob0 = xhb1 + ND;
  unsigned short* xob1 = xob0 + ND;        // also holds bf16(xo_in) initially
  unsigned short* hSb0 = xob1 + ND;
  unsigned short* hSb1 = hSb0 + ND;
  unsigned short* Wtb  = hSb1 + ND;        // 2*8*65536 bf16
  int* cur     = (int*)(Wtb + (size_t)2*LAY*DIM*DIM);   // 3*NNODE cursors
  int* rp_ho   = cur + 3*NNODE;
  int* rp_oh   = rp_ho + NNODE + 1;
  int* rp_src  = rp_oh + NNODE + 1;
  int* bsum    = rp_src + NNODE + 1;       // 3*SCB
  int* boff    = bsum + 3*SCB;             // 3*SCB
  int* phist   = boff + 3*SCB;             // 3*HNW*HC*HW ints (~12.6MB)
  // overlay on phist after scanC (dead): per-layer logit/softmax buffers
  uint2*  lgsrc_ho = (uint2*)phist;                 // E uint2 (4MB)
  uint2*  lgsrc_oh = lgsrc_ho + EDG;                // E uint2 (4MB)
  float2* msb_ho   = (float2*)(lgsrc_oh + EDG);     // NNODE float2
  float2* msb_oh   = msb_ho + NNODE;                // NNODE float2 (total 8.8MB <= 12.58MB)

  hipMemsetAsync(cur, 0, sizeof(int)*3*NNODE, stream);
  vcompute_k<<<2048, 256, 0, stream>>>(Wsrc_ho, Wdst_ho, asrc_ho, adst_ho,
                                       Wsrc_oh, Wdst_oh, asrc_oh, adst_oh, vbuf);
  wecompute_k<<<16, 64, 0, stream>>>(Wedge_ho, aedge_ho, Wedge_oh, aedge_oh, webuf);
  wtconv_k<<<4096, 256, 0, stream>>>(Wsrc_ho, Wsrc_oh, Wtb);
  histp_k<<<dim3(HC, HNW, 3), 256, 0, stream>>>(ei_ho, ei_oh, phist);
  scanA_k<<<dim3(SCB, 3), 256, 0, stream>>>(phist, bsum);
  scanB_k<<<1, 64, 0, stream>>>(bsum, boff, rp_ho, rp_oh, rp_src);
  scanC_k<<<dim3(SCB, 3), 256, 0, stream>>>(phist, boff, rp_ho, rp_oh, rp_src);
  scatter3_k<<<dim3(1954, 3), 256, 0, stream>>>(ei_ho, ei_oh, ea_ho, ea_oh,
                                                rp_ho, rp_oh, rp_src, cur,
                                                rec_ho, rec_oh, eap_src);
  // fp32->bf16 + layer-0 a_s/a_d
  xcdg_k<<<dim3(12500, 2), 256, 0, stream>>>(xh_in, xo_in, xhb1, xob1, vbuf, aset0);

  const unsigned short* xh = xhb1;
  const unsigned short* xo = xob1;
  unsigned short* xh_bufs[2] = {xhb0, xhb1};
  unsigned short* xo_bufs[2] = {xob0, xob1};
  float* asets[2] = {aset0, aset1};
  for (int l = 0; l < LAY; ++l){
    unsigned short* xo_n = xo_bufs[l & 1];
    unsigned short* xh_n = xh_bufs[l & 1];
    float* cur_a = asets[l & 1];
    float* nxt_a = asets[(l & 1) ^ 1];
    int doNext = (l < LAY-1);
    int ln = doNext ? (l+1) : l;   // valid vbuf index even when unused
    elsm_k<<<dim3(391, 2), 256, 0, stream>>>(rp_ho, rec_ho, rp_oh, rec_oh,
                                             cur_a, webuf + (size_t)l*4,
                                             lgsrc_ho, lgsrc_oh, msb_ho, msb_oh);
    gemmb2_k<<<dim3(2, 391, 2), 256, 0, stream>>>(xh, xo,
                                                  Wtb + (size_t)l*DIM*DIM,
                                                  Wtb + (size_t)(LAY + l)*DIM*DIM,
                                                  hSb0, hSb1, NNODE);
    attn2_k<<<dim3(12500, 2), 256, 0, stream>>>(rp_ho, lgsrc_ho,
                                                rp_oh, lgsrc_oh,
                                                msb_ho, msb_oh,
                                                nxt_a,
                                                hSb0, hSb1,
                                                bias_ho + (size_t)l*DIM, bias_oh + (size_t)l*DIM,
                                                xo, xh, xo_n, xh_n,
                                                vbuf + (size_t)ln*4*DIM,
                                                l > 0, doNext);
    xh = xh_n; xo = xo_n;
  }

  pool2_k<<<dim3(BB, 2), 256, 0, stream>>>(xh, xo, hbatch, obatch, hpool, opool);
  epool_k<<<BB, 256, 0, stream>>>(rp_src, hbatch, eap_src, W_emlp, b_emlp, epool);
  head_k<<<BB, 256, 0, stream>>>(hpool, opool, epool, W_p1, b_p1, W_p2, b_p2, out);
}

// Round 8
// 1461.838 us; speedup vs baseline: 1.0297x; 1.0297x over previous
//
#include <hip/hip_runtime.h>
#include <math.h>

// HELPv3: 8-layer bipartite GAT + pooling + 2 softmax heads.
// R15 = R14 resubmit (previous round was an infra failure, no measurement).
//  (1) gesm_k = gemm tiles (z<2) + elsm blocks (z=2) in ONE dispatch; elsm's
//      latency hides under gemm MFMA. LDS unioned (16KB both paths).
//  (2) sxc_k = xcdg (y<2) + scatter3 (y>=2) in ONE dispatch (independent work).
//  (3) elsm phase-2 writes normalized wgt into lgsrc.x (same exp/rcp sequence,
//      bit-identical); attn prologue is now a bare 8B load, ms buffer gone.
// Carried: readlane-scalarized gather, rcp/__expf/cvt_pk trims, 16B edge
//          records, global_load_lds GEMM staging, privatized histogram.

#define NNODE 50000
#define EDG   500000
#define DIM   256
#define LAY   8
#define BB    512
#define CC    117
#define EMBD  544
#define SCB   49          // scan blocks: 49*1024 >= 50000
#define HW    16384       // hist window (nodes), 64KB LDS
#define HC    16          // hist chunk count (private copies)
#define HNW   4           // windows: 4*16384 >= 50000
#define LDSE  4096        // elsm LDS logit slots (16KB, unioned with gemm LDS)

typedef short bf16x8 __attribute__((ext_vector_type(8)));
typedef float f32x4  __attribute__((ext_vector_type(4)));

static __device__ __forceinline__ float lrelu(float x){ return x >= 0.f ? x : 0.2f*x; }
static __device__ __forceinline__ unsigned short f2b(float f){
  unsigned int u = __float_as_uint(f);
  unsigned int r = (u + 0x7fffu + ((u >> 16) & 1u)) >> 16;   // RNE
  return (unsigned short)r;
}
static __device__ __forceinline__ float b2f(unsigned short u){
  return __uint_as_float(((unsigned int)u) << 16);
}
static __device__ __forceinline__ float blo(unsigned int u){
  return __uint_as_float(u << 16);
}
static __device__ __forceinline__ float bhi(unsigned int u){
  return __uint_as_float(u & 0xffff0000u);
}
// packed RNE f32->bf16x2 (same rounding as f2b, 1 instr instead of ~8)
static __device__ __forceinline__ unsigned cvtpk(float lo, float hi){
  unsigned r;
  asm("v_cvt_pk_bf16_f32 %0, %1, %2" : "=v"(r) : "v"(lo), "v"(hi));
  return r;
}
// wave-uniform broadcasts (SGPR result; no ds_bpermute)
static __device__ __forceinline__ float rdlane_f(float v, int id){
  return __uint_as_float(__builtin_amdgcn_readlane(__float_as_uint(v), id));
}
static __device__ __forceinline__ int rdlane_i(int v, int id){
  return __builtin_amdgcn_readlane(v, id);
}

static __device__ __forceinline__ void gload_lds16(const void* g, void* l){
  __builtin_amdgcn_global_load_lds((const __attribute__((address_space(1))) void*)g,
                                   (__attribute__((address_space(3))) void*)l,
                                   16, 0, 0);
}

// v[k] = sum_j W[k*256+j]*a[j] for 32 (l,rel,which) combos; one wave per output k
__global__ void vcompute_k(const float* __restrict__ Wsho, const float* __restrict__ Wdho,
                           const float* __restrict__ asho, const float* __restrict__ adho,
                           const float* __restrict__ Wsoh, const float* __restrict__ Wdoh,
                           const float* __restrict__ asoh, const float* __restrict__ adoh,
                           float* __restrict__ vbuf){
  int gid = blockIdx.x*blockDim.x + threadIdx.x;
  int wv = gid >> 6, lane = gid & 63;
  if (wv >= 32*DIM) return;
  int p = wv >> 8, k = wv & 255;
  int which = p & 1, rel = (p>>1)&1, l = p>>2;
  const float* W; const float* a;
  if (rel==0){ W = which? Wdho : Wsho; a = which? adho : asho; }
  else       { W = which? Wdoh : Wsoh; a = which? adoh : asoh; }
  W += (size_t)l*DIM*DIM; a += (size_t)l*DIM;
  const float4* w4 = (const float4*)(W + (size_t)k*DIM);
  const float4* a4 = (const float4*)a;
  float4 wv4 = w4[lane], av4 = a4[lane];
  float s = wv4.x*av4.x + wv4.y*av4.y + wv4.z*av4.z + wv4.w*av4.w;
  for (int off=32; off; off>>=1) s += __shfl_xor(s, off);
  if (lane==0) vbuf[(size_t)p*DIM + k] = s;
}

__global__ void wecompute_k(const float* __restrict__ Weho, const float* __restrict__ aeho,
                            const float* __restrict__ Weoh, const float* __restrict__ aeoh,
                            float* __restrict__ webuf){
  int blk = blockIdx.x;            // l*2 + rel
  int rel = blk & 1, l = blk >> 1;
  const float* We = rel? Weoh : Weho;
  const float* ae = rel? aeoh : aeho;
  int lane = threadIdx.x;          // 64
  const float4* w0 = (const float4*)(We + (size_t)l*2*DIM);
  const float4* w1 = (const float4*)(We + (size_t)l*2*DIM + DIM);
  const float4* a4 = (const float4*)(ae + (size_t)l*DIM);
  float4 av = a4[lane], x0 = w0[lane], x1 = w1[lane];
  float s0 = x0.x*av.x + x0.y*av.y + x0.z*av.z + x0.w*av.w;
  float s1 = x1.x*av.x + x1.y*av.y + x1.z*av.z + x1.w*av.w;
  for (int off=32; off; off>>=1){ s0 += __shfl_xor(s0, off); s1 += __shfl_xor(s1, off); }
  if (lane==0){ webuf[blk*2] = s0; webuf[blk*2+1] = s1; }
}

// privatized histogram: block (x=chunk, y=window, z=array) counts its chunk's
// in-window keys in LDS, writes private copy (coalesced, no atomics).
// phist[((z*HNW + y)*HC + x)*HW + off]
__global__ void histp_k(const int* __restrict__ ei_ho, const int* __restrict__ ei_oh,
                        int* __restrict__ phist){
  __shared__ int h[HW];
  int x = blockIdx.x, y = blockIdx.y, z = blockIdx.z, t = threadIdx.x;
  for (int i=t; i<HW; i+=256) h[i] = 0;
  __syncthreads();
  const int* keys = (z==0)? (ei_ho + EDG) : (z==1)? (ei_oh + EDG) : ei_ho;
  int lo = y << 14;
  int e0 = x * (EDG/HC), e1 = e0 + (EDG/HC);
  for (int e = e0 + t; e < e1; e += 256){
    int k = keys[e] - lo;
    if ((unsigned)k < (unsigned)HW) atomicAdd(&h[k], 1);
  }
  __syncthreads();
  int* dst = phist + (size_t)(((z*HNW + y)*HC + x))*HW;
  for (int i=t; i<HW; i+=256) dst[i] = h[i];
}

static __device__ __forceinline__ int4 phist_sum4(const int* __restrict__ phist,
                                                  int z, int idx){
  int win = idx >> 14, off = idx & (HW-1);
  const int* base = phist + (size_t)((z*HNW + win)*HC)*HW + off;
  int4 s = make_int4(0,0,0,0);
  #pragma unroll
  for (int c=0;c<HC;c++){
    int4 v = *(const int4*)(base + (size_t)c*HW);
    s.x += v.x; s.y += v.y; s.z += v.z; s.w += v.w;
  }
  return s;
}

// Phase A: per-block sums (grid SCB x 3, 256 thr, 4 elem/thr)
__global__ void scanA_k(const int* __restrict__ phist, int* __restrict__ bsum){
  __shared__ int sh[256];
  int y = blockIdx.y, b = blockIdx.x, t = threadIdx.x;
  int idx = b*1024 + t*4;
  int s = 0;
  if (idx + 3 < NNODE){
    int4 v = phist_sum4(phist, y, idx);
    s = v.x + v.y + v.z + v.w;
  } else {
    for (int j=0;j<4;j++) if (idx+j < NNODE){
      int win = (idx+j) >> 14, off = (idx+j) & (HW-1);
      for (int c=0;c<HC;c++) s += phist[(size_t)((y*HNW+win)*HC+c)*HW + off];
    }
  }
  sh[t] = s; __syncthreads();
  for (int off=128; off; off>>=1){ if (t<off) sh[t] += sh[t+off]; __syncthreads(); }
  if (t==0) bsum[y*SCB + b] = sh[0];
}

__global__ void scanB_k(int* __restrict__ bsum, int* __restrict__ boff,
                        int* __restrict__ rp0, int* __restrict__ rp1, int* __restrict__ rp2){
  int t = threadIdx.x;
  if (t >= 3) return;
  int run = 0;
  for (int i=0;i<SCB;i++){ boff[t*SCB+i] = run; run += bsum[t*SCB+i]; }
  int* rp = (t==0)? rp0 : (t==1)? rp1 : rp2;
  rp[NNODE] = run;
}

__global__ void scanC_k(const int* __restrict__ phist, const int* __restrict__ boff,
                        int* __restrict__ rp0, int* __restrict__ rp1, int* __restrict__ rp2){
  __shared__ int sh[256];
  int y = blockIdx.y, b = blockIdx.x, t = threadIdx.x;
  int* rp = (y==0)? rp0 : (y==1)? rp1 : rp2;
  int idx = b*1024 + t*4;
  int c[4] = {0,0,0,0};
  if (idx + 3 < NNODE){
    int4 v = phist_sum4(phist, y, idx);
    c[0]=v.x; c[1]=v.y; c[2]=v.z; c[3]=v.w;
  } else {
    for (int j=0;j<4;j++) if (idx+j < NNODE){
      int win = (idx+j) >> 14, off = (idx+j) & (HW-1);
      for (int cc=0;cc<HC;cc++) c[j] += phist[(size_t)((y*HNW+win)*HC+cc)*HW + off];
    }
  }
  int mysum = c[0]+c[1]+c[2]+c[3];
  sh[t] = mysum; __syncthreads();
  for (int off=1; off<256; off<<=1){
    int v = (t>=off) ? sh[t-off] : 0;
    __syncthreads();
    sh[t] += v;
    __syncthreads();
  }
  int base = boff[y*SCB + b] + (sh[t] - mysum);
  int run = 0;
  for (int j=0;j<4;j++){
    if (idx+j < NNODE) rp[idx+j] = base + run;
    run += c[j];
  }
}

// merged xcdg (y<2) + scatter3 (y>=2): independent latency-bound work overlapped.
// xcdg: fp32->bf16 convert + layer-0 a_s/a_d dots (one wave per row, z=y).
// scatter: y=2 dst(ho), y=3 dst(oh), y=4 src(ho); 16B records
// {src_as_float, ea.x, ea.y, dst_as_float} -> 1 dirty line/edge.
__global__ void sxc_k(const float* __restrict__ xh_in, const float* __restrict__ xo_in,
                      unsigned short* __restrict__ xhb, unsigned short* __restrict__ xob,
                      const float* __restrict__ vbuf, float* __restrict__ aset,
                      const int* __restrict__ ei_ho, const int* __restrict__ ei_oh,
                      const float* __restrict__ ea_ho, const float* __restrict__ ea_oh,
                      const int* __restrict__ rp0, const int* __restrict__ rp1,
                      const int* __restrict__ rp2, int* __restrict__ cur,
                      float4* __restrict__ rec0, float4* __restrict__ rec1,
                      float2* __restrict__ eap2){
  int y = blockIdx.y;
  if (y < 2){
    int gid = blockIdx.x*blockDim.x + threadIdx.x;
    int w = gid >> 6, lane = gid & 63;
    if (w >= NNODE) return;
    int z = y;
    const float* X = z? xo_in : xh_in;
    unsigned short* O = z? xob : xhb;
    const float* v1 = vbuf + (size_t)(z? 2:0)*DIM;   // as (src-role)
    const float* v2 = vbuf + (size_t)(z? 1:3)*DIM;   // ad (dst-role)
    float* o1 = aset + (size_t)(z? 2:0)*NNODE;
    float* o2 = aset + (size_t)(z? 1:3)*NNODE;
    float4 xv = ((const float4*)(X + (size_t)w*DIM))[lane];
    uint2 ob; ob.x = cvtpk(xv.x, xv.y); ob.y = cvtpk(xv.z, xv.w);
    ((uint2*)O)[(size_t)w*64 + lane] = ob;
    float4 a = ((const float4*)v1)[lane];
    float4 b = ((const float4*)v2)[lane];
    float s1 = xv.x*a.x + xv.y*a.y + xv.z*a.z + xv.w*a.w;
    float s2 = xv.x*b.x + xv.y*b.y + xv.z*b.z + xv.w*b.w;
    for (int off=32; off; off>>=1){ s1 += __shfl_xor(s1, off); s2 += __shfl_xor(s2, off); }
    if (lane==0){ o1[w] = s1; o2[w] = s2; }
  } else {
    int e = blockIdx.x*blockDim.x + threadIdx.x;
    if (e >= EDG) return;
    int yy = y - 2;
    if (yy == 0){
      int d = ei_ho[EDG + e];
      int pos = rp0[d] + atomicAdd(&cur[d], 1);
      rec0[pos] = make_float4(__int_as_float(ei_ho[e]), ea_ho[2*e], ea_ho[2*e+1],
                              __int_as_float(d));
    } else if (yy == 1){
      int d = ei_oh[EDG + e];
      int pos = rp1[d] + atomicAdd(&cur[NNODE + d], 1);
      rec1[pos] = make_float4(__int_as_float(ei_oh[e]), ea_oh[2*e], ea_oh[2*e+1],
                              __int_as_float(d));
    } else {
      int s = ei_ho[e];
      int pos = rp2[s] + atomicAdd(&cur[2*NNODE + s], 1);
      eap2[pos] = make_float2(ea_ho[2*e], ea_ho[2*e+1]);
    }
  }
}

// Wt[rel][l][n][k] = bf16(W[rel][l][k][n])
__global__ void wtconv_k(const float* __restrict__ Who, const float* __restrict__ Woh,
                         unsigned short* __restrict__ Wt){
  int gid = blockIdx.x*blockDim.x + threadIdx.x;   // < 1048576
  int rel = gid >> 19;
  int rem = gid & ((1<<19)-1);
  int l = rem >> 16;
  int idx = rem & 65535;
  int n = idx >> 8, k = idx & 255;
  const float* W = rel ? Woh : Who;
  Wt[gid] = f2b(W[(size_t)l*65536 + (size_t)k*256 + n]);
}

// merged GEMM pair (z<2) + elsm (z=2). One dispatch per layer.
// gemm z: H = x @ Wl (128x128 tile, 4 waves, global_load_lds staging).
// elsm z=2: rel=blockIdx.x, 128 nodes per blockIdx.y: edge logits ->
// lgsrc {lg,src}; then per-node m,sum; then REWRITE lgsrc.x with the
// normalized weight exp(lg-m)*rcp(s) (same sequence attn used -> bit-identical).
__global__ __launch_bounds__(256) void gesm_k(
    const unsigned short* __restrict__ A0, const unsigned short* __restrict__ A1,
    const unsigned short* __restrict__ B0, const unsigned short* __restrict__ B1,
    unsigned short* __restrict__ H0, unsigned short* __restrict__ H1, int M,
    const int* __restrict__ rp0, const float4* __restrict__ rec0,
    const int* __restrict__ rp1, const float4* __restrict__ rec1,
    const float* __restrict__ cur_a, const float* __restrict__ wepl,
    uint2* __restrict__ lgsrc0, uint2* __restrict__ lgsrc1){
  union SMu {
    struct { unsigned short As[4096]; unsigned short Bs[4096]; } g;
    float lgs[LDSE];
  };
  __shared__ __align__(16) SMu sh;

  if (blockIdx.z < 2){
    int z = blockIdx.z;
    const unsigned short* A  = z? A1 : A0;
    const unsigned short* Bt = z? B1 : B0;
    unsigned short* H        = z? H1 : H0;
    int tid = threadIdx.x;
    int col0 = blockIdx.x * 128;
    int row0 = blockIdx.y * 128;
    int w = tid >> 6, lane = tid & 63;
    int q = lane >> 4, ml = lane & 15;
    f32x4 acc[2][8];
    #pragma unroll
    for (int i=0;i<2;i++)
      #pragma unroll
      for (int j=0;j<8;j++) acc[i][j] = (f32x4){0.f,0.f,0.f,0.f};

    const unsigned short* srcA[2];
    const unsigned short* srcB[2];
    #pragma unroll
    for (int p=0;p<2;p++){
      int c = p*256 + w*64 + lane;             // linear chunk index in LDS
      int row = ((c>>6)<<4) | (c&15);
      int sq  = (c>>4)&3;
      int gr = row0 + row; if (gr >= M) gr = M-1;   // clamp; masked at store
      srcA[p] = A  + (size_t)gr*256 + sq*8;
      srcB[p] = Bt + (size_t)(col0 + row)*256 + sq*8;
    }

    for (int k0 = 0; k0 < 256; k0 += 32){
      #pragma unroll
      for (int p = 0; p < 2; ++p){
        gload_lds16(srcA[p], &sh.g.As[(size_t)(p*256 + w*64)*8]);
        gload_lds16(srcB[p], &sh.g.Bs[(size_t)(p*256 + w*64)*8]);
        srcA[p] += 32; srcB[p] += 32;
      }
      __syncthreads();
      bf16x8 a0 = *(const bf16x8*)&sh.g.As[(((2*w+0)*4 + q)*16 + ml)*8];
      bf16x8 a1 = *(const bf16x8*)&sh.g.As[(((2*w+1)*4 + q)*16 + ml)*8];
      #pragma unroll
      for (int nf = 0; nf < 8; ++nf){
        bf16x8 b = *(const bf16x8*)&sh.g.Bs[((nf*4 + q)*16 + ml)*8];
        acc[0][nf] = __builtin_amdgcn_mfma_f32_16x16x32_bf16(a0, b, acc[0][nf], 0,0,0);
        acc[1][nf] = __builtin_amdgcn_mfma_f32_16x16x32_bf16(a1, b, acc[1][nf], 0,0,0);
      }
      __syncthreads();
    }
    #pragma unroll
    for (int mf = 0; mf < 2; ++mf){
      #pragma unroll
      for (int r = 0; r < 4; ++r){
        int gr = row0 + 32*w + 16*mf + q*4 + r;
        if (gr < M){
          #pragma unroll
          for (int nf = 0; nf < 8; ++nf)
            H[(size_t)gr*256 + col0 + nf*16 + ml] = f2b(acc[mf][nf][r]);
        }
      }
    }
  } else {
    int rel = blockIdx.x;
    const int* rp = rel? rp1 : rp0;
    const float4* rec = rel? rec1 : rec0;
    const float* a_s = cur_a + (size_t)(rel? 2:0)*NNODE;
    const float* a_d = cur_a + (size_t)(rel? 3:1)*NNODE;
    float w0 = wepl[rel? 2:0], w1 = wepl[rel? 3:1];
    uint2* lgsrc = rel? lgsrc1 : lgsrc0;
    int n0 = blockIdx.y * 128;
    int n1 = n0 + 128; if (n1 > NNODE) n1 = NNODE;
    int t = threadIdx.x;
    int e0 = rp[n0], e1 = rp[n1];
    bool fit = (e1 - e0) <= LDSE;
    for (int e = e0 + t; e < e1; e += 256){
      float4 r = rec[e];
      int src = __float_as_int(r.x);
      int dst = __float_as_int(r.w);
      float lg = lrelu(a_s[src] + a_d[dst] + r.y*w0 + r.z*w1);
      lgsrc[e] = make_uint2(__float_as_uint(lg), (unsigned)src);
      if (fit) sh.lgs[e - e0] = lg;
    }
    __syncthreads();
    if (t < 128){
      int n = n0 + t;
      if (n < NNODE){
        int st = rp[n], en = rp[n+1];
        float m = -INFINITY, s = 0.f;
        if (fit){
          for (int p=st;p<en;p++) m = fmaxf(m, sh.lgs[p-e0]);
          for (int p=st;p<en;p++) s += __expf(sh.lgs[p-e0] - m);
          float inv = __builtin_amdgcn_rcpf(s);
          for (int p=st;p<en;p++)
            lgsrc[p].x = __float_as_uint(__expf(sh.lgs[p-e0] - m) * inv);
        } else {
          for (int p=st;p<en;p++) m = fmaxf(m, __uint_as_float(lgsrc[p].x));
          for (int p=st;p<en;p++) s += __expf(__uint_as_float(lgsrc[p].x) - m);
          float inv = __builtin_amdgcn_rcpf(s);
          for (int p=st;p<en;p++)
            lgsrc[p].x = __float_as_uint(__expf(__uint_as_float(lgsrc[p].x) - m) * inv);
        }
      }
    }
  }
}

// fused attn pair (y = relation). One wave per dst node. Pure gather:
// lgsrc.x already holds the normalized weight; readlane-scalarized loop.
__global__ void attn2_k(const int* __restrict__ rp0, const uint2* __restrict__ lgsrc0,
                        const int* __restrict__ rp1, const uint2* __restrict__ lgsrc1,
                        float* __restrict__ nxt_a,
                        const unsigned short* __restrict__ hs0,
                        const unsigned short* __restrict__ hs1,
                        const float* __restrict__ bias0, const float* __restrict__ bias1,
                        const unsigned short* __restrict__ xprev0,
                        const unsigned short* __restrict__ xprev1,
                        unsigned short* __restrict__ xnext0,
                        unsigned short* __restrict__ xnext1,
                        const float* __restrict__ vbl,
                        int hasRes, int doNext){
  int gid = blockIdx.x*blockDim.x + threadIdx.x;
  int w = gid >> 6, lane = gid & 63;
  if (w >= NNODE) return;
  int rel = blockIdx.y;
  const int* rowptr = rel? rp1 : rp0;
  const uint2* lgsrc = rel? lgsrc1 : lgsrc0;
  const unsigned short* hs = rel? hs1 : hs0;
  const float* bias = rel? bias1 : bias0;
  const unsigned short* xprev = rel? xprev1 : xprev0;
  unsigned short* xnext = rel? xnext1 : xnext0;

  int st = rowptr[w], en = rowptr[w+1];
  int deg = en - st;

  // hoisted independent epilogue loads (overlap their latency with the gather)
  float4 bv = ((const float4*)bias)[lane];
  uint2 rres = ((const uint2*)xprev)[(size_t)w*64 + lane];
  float4 va = ((const float4*)(vbl + (size_t)(rel? 0:2)*DIM))[lane];
  float4 vc = ((const float4*)(vbl + (size_t)(rel? 3:1)*DIM))[lane];

  float ax=0.f, ay=0.f, az=0.f, aw=0.f;
  if (deg > 0 && deg <= 64){
    int sreg = 0; float wgt = 0.f;
    if (lane < deg){
      uint2 ls = lgsrc[st + lane];
      sreg = (int)ls.y;
      wgt = __uint_as_float(ls.x);
    }
    int i = 0;
    for (; i + 7 < deg; i += 8){
      float wi[8]; const uint2* rp[8];
      #pragma unroll
      for (int j=0;j<8;j++){
        wi[j] = rdlane_f(wgt, i+j);
        rp[j] = (const uint2*)(hs + (size_t)rdlane_i(sreg, i+j)*DIM);
      }
      uint2 hv[8];
      #pragma unroll
      for (int j=0;j<8;j++) hv[j] = rp[j][lane];
      #pragma unroll
      for (int j=0;j<8;j++){
        ax += wi[j]*blo(hv[j].x); ay += wi[j]*bhi(hv[j].x);
        az += wi[j]*blo(hv[j].y); aw += wi[j]*bhi(hv[j].y);
      }
    }
    for (; i + 3 < deg; i += 4){
      float wi[4]; const uint2* rp[4];
      #pragma unroll
      for (int j=0;j<4;j++){
        wi[j] = rdlane_f(wgt, i+j);
        rp[j] = (const uint2*)(hs + (size_t)rdlane_i(sreg, i+j)*DIM);
      }
      uint2 hv[4];
      #pragma unroll
      for (int j=0;j<4;j++) hv[j] = rp[j][lane];
      #pragma unroll
      for (int j=0;j<4;j++){
        ax += wi[j]*blo(hv[j].x); ay += wi[j]*bhi(hv[j].x);
        az += wi[j]*blo(hv[j].y); aw += wi[j]*bhi(hv[j].y);
      }
    }
    for (; i < deg; ++i){
      float wi = rdlane_f(wgt, i);
      const uint2* rp = (const uint2*)(hs + (size_t)rdlane_i(sreg, i)*DIM);
      uint2 hv = rp[lane];
      ax += wi*blo(hv.x); ay += wi*bhi(hv.x);
      az += wi*blo(hv.y); aw += wi*bhi(hv.y);
    }
  } else if (deg > 64){
    for (int p = st; p < en; ++p){
      uint2 ls = lgsrc[p];
      float wgt = __uint_as_float(ls.x);
      const uint2* rp = (const uint2*)(hs + (size_t)ls.y*DIM);
      uint2 hv = rp[lane];
      ax += wgt*blo(hv.x); ay += wgt*bhi(hv.x);
      az += wgt*blo(hv.y); aw += wgt*bhi(hv.y);
    }
  }

  float resw = hasRes ? 1.f : 0.f;
  float4 o;
  o.x = fmaxf(ax + bv.x, 0.f) + resw*blo(rres.x);
  o.y = fmaxf(ay + bv.y, 0.f) + resw*bhi(rres.x);
  o.z = fmaxf(az + bv.z, 0.f) + resw*blo(rres.y);
  o.w = fmaxf(aw + bv.w, 0.f) + resw*bhi(rres.y);
  uint2 ob; ob.x = cvtpk(o.x, o.y); ob.y = cvtpk(o.z, o.w);
  ((uint2*)xnext)[(size_t)w*64 + lane] = ob;
  if (doNext){
    float s1 = o.x*va.x + o.y*va.y + o.z*va.z + o.w*va.w;
    float s2 = o.x*vc.x + o.y*vc.y + o.z*vc.z + o.w*vc.w;
    for (int off=32; off; off>>=1){ s1 += __shfl_xor(s1, off); s2 += __shfl_xor(s2, off); }
    if (lane==0){
      float* asn = nxt_a + (size_t)(rel? 0:2)*NNODE;
      float* adn = nxt_a + (size_t)(rel? 3:1)*NNODE;
      asn[w] = s1; adn[w] = s2;
    }
  }
}

__device__ __forceinline__ int lowerb(const int* a, int n, int v){
  int lo=0, hi=n;
  while (lo < hi){ int m = (lo+hi)>>1; if (a[m] < v) lo = m+1; else hi = m; }
  return lo;
}

// bf16 x pooling pair (y = h/o): block per batch, coalesced column sums
__global__ void pool2_k(const unsigned short* __restrict__ xh, const unsigned short* __restrict__ xo,
                        const int* __restrict__ hbatch, const int* __restrict__ obatch,
                        float* __restrict__ hpool, float* __restrict__ opool){
  int z = blockIdx.y;
  const unsigned short* x = z? xo : xh;
  const int* batch = z? obatch : hbatch;
  float* out = z? opool : hpool;
  int b = blockIdx.x, t = threadIdx.x; // 256
  int st = lowerb(batch, NNODE, b), en = lowerb(batch, NNODE, b+1);
  float s = 0.f;
  for (int i=st;i<en;i++) s += b2f(x[(size_t)i*DIM + t]);
  out[(size_t)b*DIM + t] = s / fmaxf((float)(en - st), 1.f);
}

// fused edge-MLP pool: hbatch sorted + src-CSR => batch b's edges contiguous.
__global__ void epool_k(const int* __restrict__ rp_src, const int* __restrict__ hbatch,
                        const float2* __restrict__ eaperm, const float* __restrict__ Wem,
                        const float* __restrict__ bem, float* __restrict__ epool){
  __shared__ float ps[8][33];
  int b = blockIdx.x, t = threadIdx.x; // 256
  int j = t & 31, g = t >> 5;
  int nst = lowerb(hbatch, NNODE, b), nen = lowerb(hbatch, NNODE, b+1);
  int est = rp_src[nst], een = rp_src[nen];
  float w0 = Wem[j], w1 = Wem[32+j], bb = bem[j];
  float s = 0.f;
  for (int p = est + g; p < een; p += 8){
    float2 e = eaperm[p];
    s += fmaxf(e.x*w0 + e.y*w1 + bb, 0.f);
  }
  ps[g][j] = s; __syncthreads();
  if (g == 0){
    float tot = 0.f;
    #pragma unroll
    for (int gg=0; gg<8; gg++) tot += ps[gg][j];
    epool[(size_t)b*32 + j] = tot / fmaxf((float)(een - est), 1.f);
  }
}

__global__ void head_k(const float* __restrict__ hpool, const float* __restrict__ opool,
                       const float* __restrict__ epool,
                       const float* __restrict__ Wp1, const float* __restrict__ bp1,
                       const float* __restrict__ Wp2, const float* __restrict__ bp2,
                       float* __restrict__ out){
  __shared__ float emb[EMBD];
  __shared__ float red[256];
  int b = blockIdx.x, t = threadIdx.x; // 256
  emb[t] = hpool[(size_t)b*DIM + t];
  emb[DIM + t] = opool[(size_t)b*DIM + t];
  if (t < 32) emb[2*DIM + t] = epool[(size_t)b*32 + t];
  __syncthreads();
  for (int h = 0; h < 2; ++h){
    const float* Wp = h? Wp2 : Wp1;
    const float* bp = h? bp2 : bp1;
    float logit = -INFINITY;
    if (t < CC){
      float s = bp[t];
      for (int k=0;k<EMBD;k++) s += emb[k]*Wp[(size_t)k*CC + t];
      logit = s;
    }
    red[t] = logit; __syncthreads();
    for (int off=128; off; off>>=1){ if (t<off) red[t] = fmaxf(red[t], red[t+off]); __syncthreads(); }
    float mx = red[0]; __syncthreads();
    float ex = (t < CC) ? expf(logit - mx) : 0.f;
    red[t] = ex; __syncthreads();
    for (int off=128; off; off>>=1){ if (t<off) red[t] += red[t+off]; __syncthreads(); }
    float sm = red[0]; __syncthreads();
    if (t < CC) out[((size_t)b*2 + h)*CC + t] = ex / sm;
  }
}

extern "C" void kernel_launch(void* const* d_in, const int* in_sizes, int n_in,
                              void* d_out, int out_size, void* d_ws, size_t ws_size,
                              hipStream_t stream) {
  (void)in_sizes; (void)n_in; (void)out_size; (void)ws_size;
  const float* xh_in   = (const float*)d_in[0];
  const float* xo_in   = (const float*)d_in[1];
  const int*   ei_ho   = (const int*)d_in[2];
  const int*   ei_oh   = (const int*)d_in[3];
  const float* ea_ho   = (const float*)d_in[4];
  const float* ea_oh   = (const float*)d_in[5];
  const int*   hbatch  = (const int*)d_in[6];
  const int*   obatch  = (const int*)d_in[7];
  const float* Wsrc_ho = (const float*)d_in[8];
  const float* Wdst_ho = (const float*)d_in[9];
  const float* asrc_ho = (const float*)d_in[10];
  const float* adst_ho = (const float*)d_in[11];
  const float* Wedge_ho= (const float*)d_in[12];
  const float* aedge_ho= (const float*)d_in[13];
  const float* bias_ho = (const float*)d_in[14];
  const float* Wsrc_oh = (const float*)d_in[15];
  const float* Wdst_oh = (const float*)d_in[16];
  const float* asrc_oh = (const float*)d_in[17];
  const float* adst_oh = (const float*)d_in[18];
  const float* Wedge_oh= (const float*)d_in[19];
  const float* aedge_oh= (const float*)d_in[20];
  const float* bias_oh = (const float*)d_in[21];
  const float* W_emlp  = (const float*)d_in[22];
  const float* b_emlp  = (const float*)d_in[23];
  const float* W_p1    = (const float*)d_in[24];
  const float* b_p1    = (const float*)d_in[25];
  const float* W_p2    = (const float*)d_in[26];
  const float* b_p2    = (const float*)d_in[27];
  float* out = (float*)d_out;

  size_t ND = (size_t)NNODE*DIM;
  float* f = (float*)d_ws;
  float* aset0 = f;                        // [asho adho asoh adoh] set 0
  float* aset1 = aset0 + 4*NNODE;          // set 1
  float* vbuf  = aset1 + 4*NNODE;          // 32*256
  float* webuf = vbuf + 32*DIM;            // 32
  float* hpool = webuf + 32;               // BB*DIM
  float* opool = hpool + (size_t)BB*DIM;
  float* epool = opool + (size_t)BB*DIM;   // BB*32
  float4* rec_ho  = (float4*)(epool + (size_t)BB*32);   // E float4 records
  float4* rec_oh  = rec_ho + EDG;
  float2* eap_src = (float2*)(rec_oh + EDG);            // E float2
  unsigned short* xhb0 = (unsigned short*)(eap_src + EDG);  // 6 x ND bf16
  unsigned short* xhb1 = xhb0 + ND;        // also holds bf16(xh_in) initially
  unsigned short* xob0 = xhb1 + ND;
  unsigned short* xob1 = xob0 + ND;        // also holds bf16(xo_in) initially
  unsigned short* hSb0 = xob1 + ND;
  unsigned short* hSb1 = hSb0 + ND;
  unsigned short* Wtb  = hSb1 + ND;        // 2*8*65536 bf16
  int* cur     = (int*)(Wtb + (size_t)2*LAY*DIM*DIM);   // 3*NNODE cursors
  int* rp_ho   = cur + 3*NNODE;
  int* rp_oh   = rp_ho + NNODE + 1;
  int* rp_src  = rp_oh + NNODE + 1;
  int* bsum    = rp_src + NNODE + 1;       // 3*SCB
  int* boff    = bsum + 3*SCB;             // 3*SCB
  int* phist   = boff + 3*SCB;             // 3*HNW*HC*HW ints (~12.6MB)
  // overlay on phist after scanC (dead): per-layer weight/src buffers
  uint2*  lgsrc_ho = (uint2*)phist;                 // E uint2 (4MB)
  uint2*  lgsrc_oh = lgsrc_ho + EDG;                // E uint2 (4MB, total 8MB <= 12.58MB)

  hipMemsetAsync(cur, 0, sizeof(int)*3*NNODE, stream);
  vcompute_k<<<2048, 256, 0, stream>>>(Wsrc_ho, Wdst_ho, asrc_ho, adst_ho,
                                       Wsrc_oh, Wdst_oh, asrc_oh, adst_oh, vbuf);
  wecompute_k<<<16, 64, 0, stream>>>(Wedge_ho, aedge_ho, Wedge_oh, aedge_oh, webuf);
  wtconv_k<<<4096, 256, 0, stream>>>(Wsrc_ho, Wsrc_oh, Wtb);
  histp_k<<<dim3(HC, HNW, 3), 256, 0, stream>>>(ei_ho, ei_oh, phist);
  scanA_k<<<dim3(SCB, 3), 256, 0, stream>>>(phist, bsum);
  scanB_k<<<1, 64, 0, stream>>>(bsum, boff, rp_ho, rp_oh, rp_src);
  scanC_k<<<dim3(SCB, 3), 256, 0, stream>>>(phist, boff, rp_ho, rp_oh, rp_src);
  // merged: xcdg (y<2) + scatter3 (y=2..4)
  sxc_k<<<dim3(12500, 5), 256, 0, stream>>>(xh_in, xo_in, xhb1, xob1, vbuf, aset0,
                                            ei_ho, ei_oh, ea_ho, ea_oh,
                                            rp_ho, rp_oh, rp_src, cur,
                                            rec_ho, rec_oh, eap_src);

  const unsigned short* xh = xhb1;
  const unsigned short* xo = xob1;
  unsigned short* xh_bufs[2] = {xhb0, xhb1};
  unsigned short* xo_bufs[2] = {xob0, xob1};
  float* asets[2] = {aset0, aset1};
  for (int l = 0; l < LAY; ++l){
    unsigned short* xo_n = xo_bufs[l & 1];
    unsigned short* xh_n = xh_bufs[l & 1];
    float* cur_a = asets[l & 1];
    float* nxt_a = asets[(l & 1) ^ 1];
    int doNext = (l < LAY-1);
    int ln = doNext ? (l+1) : l;   // valid vbuf index even when unused
    gesm_k<<<dim3(2, 391, 3), 256, 0, stream>>>(xh, xo,
                                                Wtb + (size_t)l*DIM*DIM,
                                                Wtb + (size_t)(LAY + l)*DIM*DIM,
                                                hSb0, hSb1, NNODE,
                                                rp_ho, rec_ho, rp_oh, rec_oh,
                                                cur_a, webuf + (size_t)l*4,
                                                lgsrc_ho, lgsrc_oh);
    attn2_k<<<dim3(12500, 2), 256, 0, stream>>>(rp_ho, lgsrc_ho,
                                                rp_oh, lgsrc_oh,
                                                nxt_a,
                                                hSb0, hSb1,
                                                bias_ho + (size_t)l*DIM, bias_oh + (size_t)l*DIM,
                                                xo, xh, xo_n, xh_n,
                                                vbuf + (size_t)ln*4*DIM,
                                                l > 0, doNext);
    xh = xh_n; xo = xo_n;
  }

  pool2_k<<<dim3(BB, 2), 256, 0, stream>>>(xh, xo, hbatch, obatch, hpool, opool);
  epool_k<<<BB, 256, 0, stream>>>(rp_src, hbatch, eap_src, W_emlp, b_emlp, epool);
  head_k<<<BB, 256, 0, stream>>>(hpool, opool, epool, W_p1, b_p1, W_p2, b_p2, out);
}

// Round 9
// 1446.254 us; speedup vs baseline: 1.0407x; 1.0108x over previous
//
#include <hip/hip_runtime.h>
#include <math.h>

// HELPv3: 8-layer bipartite GAT + pooling + 2 softmax heads.
// R16: (1) sxc_k flattened 1-D grid, work type = bid%5 -> xcdg & scatter blocks
//          co-resident (R15's y-split launched them serially: x varies fastest).
//      (2) gesm gemm path BK 32->64: halves barrier count (16->8/block), 32 MFMA
//          per phase; LDS 32KB (union elsm 16KB). Role moved to blockIdx.x so
//          gemm/elsm blocks interleave in launch order.
// Carried: normalized-weight lgsrc, readlane-scalarized gather, rcp/__expf/
//          cvt_pk trims, 16B edge records, global_load_lds staging, priv hist.

#define NNODE 50000
#define EDG   500000
#define DIM   256
#define LAY   8
#define BB    512
#define CC    117
#define EMBD  544
#define SCB   49          // scan blocks: 49*1024 >= 50000
#define HW    16384       // hist window (nodes), 64KB LDS
#define HC    16          // hist chunk count (private copies)
#define HNW   4           // windows: 4*16384 >= 50000
#define LDSE  4096        // elsm LDS logit slots (16KB, unioned with gemm LDS)

typedef short bf16x8 __attribute__((ext_vector_type(8)));
typedef float f32x4  __attribute__((ext_vector_type(4)));

static __device__ __forceinline__ float lrelu(float x){ return x >= 0.f ? x : 0.2f*x; }
static __device__ __forceinline__ unsigned short f2b(float f){
  unsigned int u = __float_as_uint(f);
  unsigned int r = (u + 0x7fffu + ((u >> 16) & 1u)) >> 16;   // RNE
  return (unsigned short)r;
}
static __device__ __forceinline__ float b2f(unsigned short u){
  return __uint_as_float(((unsigned int)u) << 16);
}
static __device__ __forceinline__ float blo(unsigned int u){
  return __uint_as_float(u << 16);
}
static __device__ __forceinline__ float bhi(unsigned int u){
  return __uint_as_float(u & 0xffff0000u);
}
// packed RNE f32->bf16x2 (same rounding as f2b, 1 instr instead of ~8)
static __device__ __forceinline__ unsigned cvtpk(float lo, float hi){
  unsigned r;
  asm("v_cvt_pk_bf16_f32 %0, %1, %2" : "=v"(r) : "v"(lo), "v"(hi));
  return r;
}
// wave-uniform broadcasts (SGPR result; no ds_bpermute)
static __device__ __forceinline__ float rdlane_f(float v, int id){
  return __uint_as_float(__builtin_amdgcn_readlane(__float_as_uint(v), id));
}
static __device__ __forceinline__ int rdlane_i(int v, int id){
  return __builtin_amdgcn_readlane(v, id);
}

static __device__ __forceinline__ void gload_lds16(const void* g, void* l){
  __builtin_amdgcn_global_load_lds((const __attribute__((address_space(1))) void*)g,
                                   (__attribute__((address_space(3))) void*)l,
                                   16, 0, 0);
}

// v[k] = sum_j W[k*256+j]*a[j] for 32 (l,rel,which) combos; one wave per output k
__global__ void vcompute_k(const float* __restrict__ Wsho, const float* __restrict__ Wdho,
                           const float* __restrict__ asho, const float* __restrict__ adho,
                           const float* __restrict__ Wsoh, const float* __restrict__ Wdoh,
                           const float* __restrict__ asoh, const float* __restrict__ adoh,
                           float* __restrict__ vbuf){
  int gid = blockIdx.x*blockDim.x + threadIdx.x;
  int wv = gid >> 6, lane = gid & 63;
  if (wv >= 32*DIM) return;
  int p = wv >> 8, k = wv & 255;
  int which = p & 1, rel = (p>>1)&1, l = p>>2;
  const float* W; const float* a;
  if (rel==0){ W = which? Wdho : Wsho; a = which? adho : asho; }
  else       { W = which? Wdoh : Wsoh; a = which? adoh : asoh; }
  W += (size_t)l*DIM*DIM; a += (size_t)l*DIM;
  const float4* w4 = (const float4*)(W + (size_t)k*DIM);
  const float4* a4 = (const float4*)a;
  float4 wv4 = w4[lane], av4 = a4[lane];
  float s = wv4.x*av4.x + wv4.y*av4.y + wv4.z*av4.z + wv4.w*av4.w;
  for (int off=32; off; off>>=1) s += __shfl_xor(s, off);
  if (lane==0) vbuf[(size_t)p*DIM + k] = s;
}

__global__ void wecompute_k(const float* __restrict__ Weho, const float* __restrict__ aeho,
                            const float* __restrict__ Weoh, const float* __restrict__ aeoh,
                            float* __restrict__ webuf){
  int blk = blockIdx.x;            // l*2 + rel
  int rel = blk & 1, l = blk >> 1;
  const float* We = rel? Weoh : Weho;
  const float* ae = rel? aeoh : aeho;
  int lane = threadIdx.x;          // 64
  const float4* w0 = (const float4*)(We + (size_t)l*2*DIM);
  const float4* w1 = (const float4*)(We + (size_t)l*2*DIM + DIM);
  const float4* a4 = (const float4*)(ae + (size_t)l*DIM);
  float4 av = a4[lane], x0 = w0[lane], x1 = w1[lane];
  float s0 = x0.x*av.x + x0.y*av.y + x0.z*av.z + x0.w*av.w;
  float s1 = x1.x*av.x + x1.y*av.y + x1.z*av.z + x1.w*av.w;
  for (int off=32; off; off>>=1){ s0 += __shfl_xor(s0, off); s1 += __shfl_xor(s1, off); }
  if (lane==0){ webuf[blk*2] = s0; webuf[blk*2+1] = s1; }
}

// privatized histogram: block (x=chunk, y=window, z=array) counts its chunk's
// in-window keys in LDS, writes private copy (coalesced, no atomics).
// phist[((z*HNW + y)*HC + x)*HW + off]
__global__ void histp_k(const int* __restrict__ ei_ho, const int* __restrict__ ei_oh,
                        int* __restrict__ phist){
  __shared__ int h[HW];
  int x = blockIdx.x, y = blockIdx.y, z = blockIdx.z, t = threadIdx.x;
  for (int i=t; i<HW; i+=256) h[i] = 0;
  __syncthreads();
  const int* keys = (z==0)? (ei_ho + EDG) : (z==1)? (ei_oh + EDG) : ei_ho;
  int lo = y << 14;
  int e0 = x * (EDG/HC), e1 = e0 + (EDG/HC);
  for (int e = e0 + t; e < e1; e += 256){
    int k = keys[e] - lo;
    if ((unsigned)k < (unsigned)HW) atomicAdd(&h[k], 1);
  }
  __syncthreads();
  int* dst = phist + (size_t)(((z*HNW + y)*HC + x))*HW;
  for (int i=t; i<HW; i+=256) dst[i] = h[i];
}

static __device__ __forceinline__ int4 phist_sum4(const int* __restrict__ phist,
                                                  int z, int idx){
  int win = idx >> 14, off = idx & (HW-1);
  const int* base = phist + (size_t)((z*HNW + win)*HC)*HW + off;
  int4 s = make_int4(0,0,0,0);
  #pragma unroll
  for (int c=0;c<HC;c++){
    int4 v = *(const int4*)(base + (size_t)c*HW);
    s.x += v.x; s.y += v.y; s.z += v.z; s.w += v.w;
  }
  return s;
}

// Phase A: per-block sums (grid SCB x 3, 256 thr, 4 elem/thr)
__global__ void scanA_k(const int* __restrict__ phist, int* __restrict__ bsum){
  __shared__ int sh[256];
  int y = blockIdx.y, b = blockIdx.x, t = threadIdx.x;
  int idx = b*1024 + t*4;
  int s = 0;
  if (idx + 3 < NNODE){
    int4 v = phist_sum4(phist, y, idx);
    s = v.x + v.y + v.z + v.w;
  } else {
    for (int j=0;j<4;j++) if (idx+j < NNODE){
      int win = (idx+j) >> 14, off = (idx+j) & (HW-1);
      for (int c=0;c<HC;c++) s += phist[(size_t)((y*HNW+win)*HC+c)*HW + off];
    }
  }
  sh[t] = s; __syncthreads();
  for (int off=128; off; off>>=1){ if (t<off) sh[t] += sh[t+off]; __syncthreads(); }
  if (t==0) bsum[y*SCB + b] = sh[0];
}

__global__ void scanB_k(int* __restrict__ bsum, int* __restrict__ boff,
                        int* __restrict__ rp0, int* __restrict__ rp1, int* __restrict__ rp2){
  int t = threadIdx.x;
  if (t >= 3) return;
  int run = 0;
  for (int i=0;i<SCB;i++){ boff[t*SCB+i] = run; run += bsum[t*SCB+i]; }
  int* rp = (t==0)? rp0 : (t==1)? rp1 : rp2;
  rp[NNODE] = run;
}

__global__ void scanC_k(const int* __restrict__ phist, const int* __restrict__ boff,
                        int* __restrict__ rp0, int* __restrict__ rp1, int* __restrict__ rp2){
  __shared__ int sh[256];
  int y = blockIdx.y, b = blockIdx.x, t = threadIdx.x;
  int* rp = (y==0)? rp0 : (y==1)? rp1 : rp2;
  int idx = b*1024 + t*4;
  int c[4] = {0,0,0,0};
  if (idx + 3 < NNODE){
    int4 v = phist_sum4(phist, y, idx);
    c[0]=v.x; c[1]=v.y; c[2]=v.z; c[3]=v.w;
  } else {
    for (int j=0;j<4;j++) if (idx+j < NNODE){
      int win = (idx+j) >> 14, off = (idx+j) & (HW-1);
      for (int cc=0;cc<HC;cc++) c[j] += phist[(size_t)((y*HNW+win)*HC+cc)*HW + off];
    }
  }
  int mysum = c[0]+c[1]+c[2]+c[3];
  sh[t] = mysum; __syncthreads();
  for (int off=1; off<256; off<<=1){
    int v = (t>=off) ? sh[t-off] : 0;
    __syncthreads();
    sh[t] += v;
    __syncthreads();
  }
  int base = boff[y*SCB + b] + (sh[t] - mysum);
  int run = 0;
  for (int j=0;j<4;j++){
    if (idx+j < NNODE) rp[idx+j] = base + run;
    run += c[j];
  }
}

// merged xcdg + scatter3, FLAT 1-D grid, work type = bid%5 so both kinds of
// blocks are co-resident (y-split launched them serially).
// type<2: fp32->bf16 convert + layer-0 a_s/a_d dots (one wave per row, z=type).
// type>=2: scatter y=2 dst(ho), y=3 dst(oh), y=4 src(ho); 16B records
// {src_as_float, ea.x, ea.y, dst_as_float} -> 1 dirty line/edge.
__global__ void sxc_k(const float* __restrict__ xh_in, const float* __restrict__ xo_in,
                      unsigned short* __restrict__ xhb, unsigned short* __restrict__ xob,
                      const float* __restrict__ vbuf, float* __restrict__ aset,
                      const int* __restrict__ ei_ho, const int* __restrict__ ei_oh,
                      const float* __restrict__ ea_ho, const float* __restrict__ ea_oh,
                      const int* __restrict__ rp0, const int* __restrict__ rp1,
                      const int* __restrict__ rp2, int* __restrict__ cur,
                      float4* __restrict__ rec0, float4* __restrict__ rec1,
                      float2* __restrict__ eap2){
  int bid = blockIdx.x;
  int y = bid % 5, x = bid / 5;
  if (y < 2){
    int gid = x*blockDim.x + threadIdx.x;
    int w = gid >> 6, lane = gid & 63;
    if (w >= NNODE) return;
    int z = y;
    const float* X = z? xo_in : xh_in;
    unsigned short* O = z? xob : xhb;
    const float* v1 = vbuf + (size_t)(z? 2:0)*DIM;   // as (src-role)
    const float* v2 = vbuf + (size_t)(z? 1:3)*DIM;   // ad (dst-role)
    float* o1 = aset + (size_t)(z? 2:0)*NNODE;
    float* o2 = aset + (size_t)(z? 1:3)*NNODE;
    float4 xv = ((const float4*)(X + (size_t)w*DIM))[lane];
    uint2 ob; ob.x = cvtpk(xv.x, xv.y); ob.y = cvtpk(xv.z, xv.w);
    ((uint2*)O)[(size_t)w*64 + lane] = ob;
    float4 a = ((const float4*)v1)[lane];
    float4 b = ((const float4*)v2)[lane];
    float s1 = xv.x*a.x + xv.y*a.y + xv.z*a.z + xv.w*a.w;
    float s2 = xv.x*b.x + xv.y*b.y + xv.z*b.z + xv.w*b.w;
    for (int off=32; off; off>>=1){ s1 += __shfl_xor(s1, off); s2 += __shfl_xor(s2, off); }
    if (lane==0){ o1[w] = s1; o2[w] = s2; }
  } else {
    int e = x*blockDim.x + threadIdx.x;
    if (e >= EDG) return;
    int yy = y - 2;
    if (yy == 0){
      int d = ei_ho[EDG + e];
      int pos = rp0[d] + atomicAdd(&cur[d], 1);
      rec0[pos] = make_float4(__int_as_float(ei_ho[e]), ea_ho[2*e], ea_ho[2*e+1],
                              __int_as_float(d));
    } else if (yy == 1){
      int d = ei_oh[EDG + e];
      int pos = rp1[d] + atomicAdd(&cur[NNODE + d], 1);
      rec1[pos] = make_float4(__int_as_float(ei_oh[e]), ea_oh[2*e], ea_oh[2*e+1],
                              __int_as_float(d));
    } else {
      int s = ei_ho[e];
      int pos = rp2[s] + atomicAdd(&cur[2*NNODE + s], 1);
      eap2[pos] = make_float2(ea_ho[2*e], ea_ho[2*e+1]);
    }
  }
}

// Wt[rel][l][n][k] = bf16(W[rel][l][k][n])
__global__ void wtconv_k(const float* __restrict__ Who, const float* __restrict__ Woh,
                         unsigned short* __restrict__ Wt){
  int gid = blockIdx.x*blockDim.x + threadIdx.x;   // < 1048576
  int rel = gid >> 19;
  int rem = gid & ((1<<19)-1);
  int l = rem >> 16;
  int idx = rem & 65535;
  int n = idx >> 8, k = idx & 255;
  const float* W = rel ? Woh : Who;
  Wt[gid] = f2b(W[(size_t)l*65536 + (size_t)k*256 + n]);
}

// merged GEMM pair + elsm. Role on blockIdx.x (fastest) so gemm/elsm interleave.
// role 0/1: H = x @ Wl, 128x128 tile, BK=64 (8 barriers/block, 32 MFMA/phase).
//   LDS chunk c (0..1023): row=((c>>7)<<4)|(c&15), sq=(c>>4)&7 (bijection).
// role 2: elsm; rel = blockIdx.z, 128 nodes per blockIdx.y: edge logits ->
//   lgsrc {lg,src}; per-node m,sum; REWRITE lgsrc.x with normalized weight.
__global__ __launch_bounds__(256) void gesm_k(
    const unsigned short* __restrict__ A0, const unsigned short* __restrict__ A1,
    const unsigned short* __restrict__ B0, const unsigned short* __restrict__ B1,
    unsigned short* __restrict__ H0, unsigned short* __restrict__ H1, int M,
    const int* __restrict__ rp0, const float4* __restrict__ rec0,
    const int* __restrict__ rp1, const float4* __restrict__ rec1,
    const float* __restrict__ cur_a, const float* __restrict__ wepl,
    uint2* __restrict__ lgsrc0, uint2* __restrict__ lgsrc1){
  union SMu {
    struct { unsigned short As[8192]; unsigned short Bs[8192]; } g;  // 32KB
    float lgs[LDSE];                                                 // 16KB
  };
  __shared__ __align__(16) SMu sh;

  int role = blockIdx.x;
  if (role < 2){
    int z = role;
    const unsigned short* A  = z? A1 : A0;
    const unsigned short* Bt = z? B1 : B0;
    unsigned short* H        = z? H1 : H0;
    int tid = threadIdx.x;
    int col0 = blockIdx.z * 128;
    int row0 = blockIdx.y * 128;
    int w = tid >> 6, lane = tid & 63;
    int q = lane >> 4, ml = lane & 15;
    f32x4 acc[2][8];
    #pragma unroll
    for (int i=0;i<2;i++)
      #pragma unroll
      for (int j=0;j<8;j++) acc[i][j] = (f32x4){0.f,0.f,0.f,0.f};

    // per-lane permuted global sources, 4 staging issues (1024 chunks of 16B)
    const unsigned short* srcA[4];
    const unsigned short* srcB[4];
    #pragma unroll
    for (int p=0;p<4;p++){
      int c = p*256 + w*64 + lane;             // linear chunk index in LDS
      int row = ((c>>7)<<4) | (c&15);
      int sq  = (c>>4)&7;
      int gr = row0 + row; if (gr >= M) gr = M-1;   // clamp; masked at store
      srcA[p] = A  + (size_t)gr*256 + sq*8;
      srcB[p] = Bt + (size_t)(col0 + row)*256 + sq*8;
    }

    for (int k0 = 0; k0 < 256; k0 += 64){
      #pragma unroll
      for (int p = 0; p < 4; ++p){
        gload_lds16(srcA[p], &sh.g.As[(size_t)(p*256 + w*64)*8]);
        gload_lds16(srcB[p], &sh.g.Bs[(size_t)(p*256 + w*64)*8]);
        srcA[p] += 64; srcB[p] += 64;
      }
      __syncthreads();
      #pragma unroll
      for (int kk = 0; kk < 2; ++kk){
        bf16x8 a0 = *(const bf16x8*)&sh.g.As[((((2*w+0)*8) + kk*4 + q)*16 + ml)*8];
        bf16x8 a1 = *(const bf16x8*)&sh.g.As[((((2*w+1)*8) + kk*4 + q)*16 + ml)*8];
        #pragma unroll
        for (int nf = 0; nf < 8; ++nf){
          bf16x8 b = *(const bf16x8*)&sh.g.Bs[((nf*8 + kk*4 + q)*16 + ml)*8];
          acc[0][nf] = __builtin_amdgcn_mfma_f32_16x16x32_bf16(a0, b, acc[0][nf], 0,0,0);
          acc[1][nf] = __builtin_amdgcn_mfma_f32_16x16x32_bf16(a1, b, acc[1][nf], 0,0,0);
        }
      }
      __syncthreads();
    }
    #pragma unroll
    for (int mf = 0; mf < 2; ++mf){
      #pragma unroll
      for (int r = 0; r < 4; ++r){
        int gr = row0 + 32*w + 16*mf + q*4 + r;
        if (gr < M){
          #pragma unroll
          for (int nf = 0; nf < 8; ++nf)
            H[(size_t)gr*256 + col0 + nf*16 + ml] = f2b(acc[mf][nf][r]);
        }
      }
    }
  } else {
    int rel = blockIdx.z;
    const int* rp = rel? rp1 : rp0;
    const float4* rec = rel? rec1 : rec0;
    const float* a_s = cur_a + (size_t)(rel? 2:0)*NNODE;
    const float* a_d = cur_a + (size_t)(rel? 3:1)*NNODE;
    float w0 = wepl[rel? 2:0], w1 = wepl[rel? 3:1];
    uint2* lgsrc = rel? lgsrc1 : lgsrc0;
    int n0 = blockIdx.y * 128;
    int n1 = n0 + 128; if (n1 > NNODE) n1 = NNODE;
    int t = threadIdx.x;
    int e0 = rp[n0], e1 = rp[n1];
    bool fit = (e1 - e0) <= LDSE;
    for (int e = e0 + t; e < e1; e += 256){
      float4 r = rec[e];
      int src = __float_as_int(r.x);
      int dst = __float_as_int(r.w);
      float lg = lrelu(a_s[src] + a_d[dst] + r.y*w0 + r.z*w1);
      lgsrc[e] = make_uint2(__float_as_uint(lg), (unsigned)src);
      if (fit) sh.lgs[e - e0] = lg;
    }
    __syncthreads();
    if (t < 128){
      int n = n0 + t;
      if (n < NNODE){
        int st = rp[n], en = rp[n+1];
        float m = -INFINITY, s = 0.f;
        if (fit){
          for (int p=st;p<en;p++) m = fmaxf(m, sh.lgs[p-e0]);
          for (int p=st;p<en;p++) s += __expf(sh.lgs[p-e0] - m);
          float inv = __builtin_amdgcn_rcpf(s);
          for (int p=st;p<en;p++)
            lgsrc[p].x = __float_as_uint(__expf(sh.lgs[p-e0] - m) * inv);
        } else {
          for (int p=st;p<en;p++) m = fmaxf(m, __uint_as_float(lgsrc[p].x));
          for (int p=st;p<en;p++) s += __expf(__uint_as_float(lgsrc[p].x) - m);
          float inv = __builtin_amdgcn_rcpf(s);
          for (int p=st;p<en;p++)
            lgsrc[p].x = __float_as_uint(__expf(__uint_as_float(lgsrc[p].x) - m) * inv);
        }
      }
    }
  }
}

// fused attn pair (y = relation). One wave per dst node. Pure gather:
// lgsrc.x already holds the normalized weight; readlane-scalarized loop.
__global__ void attn2_k(const int* __restrict__ rp0, const uint2* __restrict__ lgsrc0,
                        const int* __restrict__ rp1, const uint2* __restrict__ lgsrc1,
                        float* __restrict__ nxt_a,
                        const unsigned short* __restrict__ hs0,
                        const unsigned short* __restrict__ hs1,
                        const float* __restrict__ bias0, const float* __restrict__ bias1,
                        const unsigned short* __restrict__ xprev0,
                        const unsigned short* __restrict__ xprev1,
                        unsigned short* __restrict__ xnext0,
                        unsigned short* __restrict__ xnext1,
                        const float* __restrict__ vbl,
                        int hasRes, int doNext){
  int gid = blockIdx.x*blockDim.x + threadIdx.x;
  int w = gid >> 6, lane = gid & 63;
  if (w >= NNODE) return;
  int rel = blockIdx.y;
  const int* rowptr = rel? rp1 : rp0;
  const uint2* lgsrc = rel? lgsrc1 : lgsrc0;
  const unsigned short* hs = rel? hs1 : hs0;
  const float* bias = rel? bias1 : bias0;
  const unsigned short* xprev = rel? xprev1 : xprev0;
  unsigned short* xnext = rel? xnext1 : xnext0;

  int st = rowptr[w], en = rowptr[w+1];
  int deg = en - st;

  // hoisted independent epilogue loads (overlap their latency with the gather)
  float4 bv = ((const float4*)bias)[lane];
  uint2 rres = ((const uint2*)xprev)[(size_t)w*64 + lane];
  float4 va = ((const float4*)(vbl + (size_t)(rel? 0:2)*DIM))[lane];
  float4 vc = ((const float4*)(vbl + (size_t)(rel? 3:1)*DIM))[lane];

  float ax=0.f, ay=0.f, az=0.f, aw=0.f;
  if (deg > 0 && deg <= 64){
    int sreg = 0; float wgt = 0.f;
    if (lane < deg){
      uint2 ls = lgsrc[st + lane];
      sreg = (int)ls.y;
      wgt = __uint_as_float(ls.x);
    }
    int i = 0;
    for (; i + 7 < deg; i += 8){
      float wi[8]; const uint2* rp[8];
      #pragma unroll
      for (int j=0;j<8;j++){
        wi[j] = rdlane_f(wgt, i+j);
        rp[j] = (const uint2*)(hs + (size_t)rdlane_i(sreg, i+j)*DIM);
      }
      uint2 hv[8];
      #pragma unroll
      for (int j=0;j<8;j++) hv[j] = rp[j][lane];
      #pragma unroll
      for (int j=0;j<8;j++){
        ax += wi[j]*blo(hv[j].x); ay += wi[j]*bhi(hv[j].x);
        az += wi[j]*blo(hv[j].y); aw += wi[j]*bhi(hv[j].y);
      }
    }
    for (; i + 3 < deg; i += 4){
      float wi[4]; const uint2* rp[4];
      #pragma unroll
      for (int j=0;j<4;j++){
        wi[j] = rdlane_f(wgt, i+j);
        rp[j] = (const uint2*)(hs + (size_t)rdlane_i(sreg, i+j)*DIM);
      }
      uint2 hv[4];
      #pragma unroll
      for (int j=0;j<4;j++) hv[j] = rp[j][lane];
      #pragma unroll
      for (int j=0;j<4;j++){
        ax += wi[j]*blo(hv[j].x); ay += wi[j]*bhi(hv[j].x);
        az += wi[j]*blo(hv[j].y); aw += wi[j]*bhi(hv[j].y);
      }
    }
    for (; i < deg; ++i){
      float wi = rdlane_f(wgt, i);
      const uint2* rp = (const uint2*)(hs + (size_t)rdlane_i(sreg, i)*DIM);
      uint2 hv = rp[lane];
      ax += wi*blo(hv.x); ay += wi*bhi(hv.x);
      az += wi*blo(hv.y); aw += wi*bhi(hv.y);
    }
  } else if (deg > 64){
    for (int p = st; p < en; ++p){
      uint2 ls = lgsrc[p];
      float wgt = __uint_as_float(ls.x);
      const uint2* rp = (const uint2*)(hs + (size_t)ls.y*DIM);
      uint2 hv = rp[lane];
      ax += wgt*blo(hv.x); ay += wgt*bhi(hv.x);
      az += wgt*blo(hv.y); aw += wgt*bhi(hv.y);
    }
  }

  float resw = hasRes ? 1.f : 0.f;
  float4 o;
  o.x = fmaxf(ax + bv.x, 0.f) + resw*blo(rres.x);
  o.y = fmaxf(ay + bv.y, 0.f) + resw*bhi(rres.x);
  o.z = fmaxf(az + bv.z, 0.f) + resw*blo(rres.y);
  o.w = fmaxf(aw + bv.w, 0.f) + resw*bhi(rres.y);
  uint2 ob; ob.x = cvtpk(o.x, o.y); ob.y = cvtpk(o.z, o.w);
  ((uint2*)xnext)[(size_t)w*64 + lane] = ob;
  if (doNext){
    float s1 = o.x*va.x + o.y*va.y + o.z*va.z + o.w*va.w;
    float s2 = o.x*vc.x + o.y*vc.y + o.z*vc.z + o.w*vc.w;
    for (int off=32; off; off>>=1){ s1 += __shfl_xor(s1, off); s2 += __shfl_xor(s2, off); }
    if (lane==0){
      float* asn = nxt_a + (size_t)(rel? 0:2)*NNODE;
      float* adn = nxt_a + (size_t)(rel? 3:1)*NNODE;
      asn[w] = s1; adn[w] = s2;
    }
  }
}

__device__ __forceinline__ int lowerb(const int* a, int n, int v){
  int lo=0, hi=n;
  while (lo < hi){ int m = (lo+hi)>>1; if (a[m] < v) lo = m+1; else hi = m; }
  return lo;
}

// bf16 x pooling pair (y = h/o): block per batch, coalesced column sums
__global__ void pool2_k(const unsigned short* __restrict__ xh, const unsigned short* __restrict__ xo,
                        const int* __restrict__ hbatch, const int* __restrict__ obatch,
                        float* __restrict__ hpool, float* __restrict__ opool){
  int z = blockIdx.y;
  const unsigned short* x = z? xo : xh;
  const int* batch = z? obatch : hbatch;
  float* out = z? opool : hpool;
  int b = blockIdx.x, t = threadIdx.x; // 256
  int st = lowerb(batch, NNODE, b), en = lowerb(batch, NNODE, b+1);
  float s = 0.f;
  for (int i=st;i<en;i++) s += b2f(x[(size_t)i*DIM + t]);
  out[(size_t)b*DIM + t] = s / fmaxf((float)(en - st), 1.f);
}

// fused edge-MLP pool: hbatch sorted + src-CSR => batch b's edges contiguous.
__global__ void epool_k(const int* __restrict__ rp_src, const int* __restrict__ hbatch,
                        const float2* __restrict__ eaperm, const float* __restrict__ Wem,
                        const float* __restrict__ bem, float* __restrict__ epool){
  __shared__ float ps[8][33];
  int b = blockIdx.x, t = threadIdx.x; // 256
  int j = t & 31, g = t >> 5;
  int nst = lowerb(hbatch, NNODE, b), nen = lowerb(hbatch, NNODE, b+1);
  int est = rp_src[nst], een = rp_src[nen];
  float w0 = Wem[j], w1 = Wem[32+j], bb = bem[j];
  float s = 0.f;
  for (int p = est + g; p < een; p += 8){
    float2 e = eaperm[p];
    s += fmaxf(e.x*w0 + e.y*w1 + bb, 0.f);
  }
  ps[g][j] = s; __syncthreads();
  if (g == 0){
    float tot = 0.f;
    #pragma unroll
    for (int gg=0; gg<8; gg++) tot += ps[gg][j];
    epool[(size_t)b*32 + j] = tot / fmaxf((float)(een - est), 1.f);
  }
}

__global__ void head_k(const float* __restrict__ hpool, const float* __restrict__ opool,
                       const float* __restrict__ epool,
                       const float* __restrict__ Wp1, const float* __restrict__ bp1,
                       const float* __restrict__ Wp2, const float* __restrict__ bp2,
                       float* __restrict__ out){
  __shared__ float emb[EMBD];
  __shared__ float red[256];
  int b = blockIdx.x, t = threadIdx.x; // 256
  emb[t] = hpool[(size_t)b*DIM + t];
  emb[DIM + t] = opool[(size_t)b*DIM + t];
  if (t < 32) emb[2*DIM + t] = epool[(size_t)b*32 + t];
  __syncthreads();
  for (int h = 0; h < 2; ++h){
    const float* Wp = h? Wp2 : Wp1;
    const float* bp = h? bp2 : bp1;
    float logit = -INFINITY;
    if (t < CC){
      float s = bp[t];
      for (int k=0;k<EMBD;k++) s += emb[k]*Wp[(size_t)k*CC + t];
      logit = s;
    }
    red[t] = logit; __syncthreads();
    for (int off=128; off; off>>=1){ if (t<off) red[t] = fmaxf(red[t], red[t+off]); __syncthreads(); }
    float mx = red[0]; __syncthreads();
    float ex = (t < CC) ? expf(logit - mx) : 0.f;
    red[t] = ex; __syncthreads();
    for (int off=128; off; off>>=1){ if (t<off) red[t] += red[t+off]; __syncthreads(); }
    float sm = red[0]; __syncthreads();
    if (t < CC) out[((size_t)b*2 + h)*CC + t] = ex / sm;
  }
}

extern "C" void kernel_launch(void* const* d_in, const int* in_sizes, int n_in,
                              void* d_out, int out_size, void* d_ws, size_t ws_size,
                              hipStream_t stream) {
  (void)in_sizes; (void)n_in; (void)out_size; (void)ws_size;
  const float* xh_in   = (const float*)d_in[0];
  const float* xo_in   = (const float*)d_in[1];
  const int*   ei_ho   = (const int*)d_in[2];
  const int*   ei_oh   = (const int*)d_in[3];
  const float* ea_ho   = (const float*)d_in[4];
  const float* ea_oh   = (const float*)d_in[5];
  const int*   hbatch  = (const int*)d_in[6];
  const int*   obatch  = (const int*)d_in[7];
  const float* Wsrc_ho = (const float*)d_in[8];
  const float* Wdst_ho = (const float*)d_in[9];
  const float* asrc_ho = (const float*)d_in[10];
  const float* adst_ho = (const float*)d_in[11];
  const float* Wedge_ho= (const float*)d_in[12];
  const float* aedge_ho= (const float*)d_in[13];
  const float* bias_ho = (const float*)d_in[14];
  const float* Wsrc_oh = (const float*)d_in[15];
  const float* Wdst_oh = (const float*)d_in[16];
  const float* asrc_oh = (const float*)d_in[17];
  const float* adst_oh = (const float*)d_in[18];
  const float* Wedge_oh= (const float*)d_in[19];
  const float* aedge_oh= (const float*)d_in[20];
  const float* bias_oh = (const float*)d_in[21];
  const float* W_emlp  = (const float*)d_in[22];
  const float* b_emlp  = (const float*)d_in[23];
  const float* W_p1    = (const float*)d_in[24];
  const float* b_p1    = (const float*)d_in[25];
  const float* W_p2    = (const float*)d_in[26];
  const float* b_p2    = (const float*)d_in[27];
  float* out = (float*)d_out;

  size_t ND = (size_t)NNODE*DIM;
  float* f = (float*)d_ws;
  float* aset0 = f;                        // [asho adho asoh adoh] set 0
  float* aset1 = aset0 + 4*NNODE;          // set 1
  float* vbuf  = aset1 + 4*NNODE;          // 32*256
  float* webuf = vbuf + 32*DIM;            // 32
  float* hpool = webuf + 32;               // BB*DIM
  float* opool = hpool + (size_t)BB*DIM;
  float* epool = opool + (size_t)BB*DIM;   // BB*32
  float4* rec_ho  = (float4*)(epool + (size_t)BB*32);   // E float4 records
  float4* rec_oh  = rec_ho + EDG;
  float2* eap_src = (float2*)(rec_oh + EDG);            // E float2
  unsigned short* xhb0 = (unsigned short*)(eap_src + EDG);  // 6 x ND bf16
  unsigned short* xhb1 = xhb0 + ND;        // also holds bf16(xh_in) initially
  unsigned short* xob0 = xhb1 + ND;
  unsigned short* xob1 = xob0 + ND;        // also holds bf16(xo_in) initially
  unsigned short* hSb0 = xob1 + ND;
  unsigned short* hSb1 = hSb0 + ND;
  unsigned short* Wtb  = hSb1 + ND;        // 2*8*65536 bf16
  int* cur     = (int*)(Wtb + (size_t)2*LAY*DIM*DIM);   // 3*NNODE cursors
  int* rp_ho   = cur + 3*NNODE;
  int* rp_oh   = rp_ho + NNODE + 1;
  int* rp_src  = rp_oh + NNODE + 1;
  int* bsum    = rp_src + NNODE + 1;       // 3*SCB
  int* boff    = bsum + 3*SCB;             // 3*SCB
  int* phist   = boff + 3*SCB;             // 3*HNW*HC*HW ints (~12.6MB)
  // overlay on phist after scanC (dead): per-layer weight/src buffers
  uint2*  lgsrc_ho = (uint2*)phist;                 // E uint2 (4MB)
  uint2*  lgsrc_oh = lgsrc_ho + EDG;                // E uint2 (4MB, total 8MB <= 12.58MB)

  hipMemsetAsync(cur, 0, sizeof(int)*3*NNODE, stream);
  vcompute_k<<<2048, 256, 0, stream>>>(Wsrc_ho, Wdst_ho, asrc_ho, adst_ho,
                                       Wsrc_oh, Wdst_oh, asrc_oh, adst_oh, vbuf);
  wecompute_k<<<16, 64, 0, stream>>>(Wedge_ho, aedge_ho, Wedge_oh, aedge_oh, webuf);
  wtconv_k<<<4096, 256, 0, stream>>>(Wsrc_ho, Wsrc_oh, Wtb);
  histp_k<<<dim3(HC, HNW, 3), 256, 0, stream>>>(ei_ho, ei_oh, phist);
  scanA_k<<<dim3(SCB, 3), 256, 0, stream>>>(phist, bsum);
  scanB_k<<<1, 64, 0, stream>>>(bsum, boff, rp_ho, rp_oh, rp_src);
  scanC_k<<<dim3(SCB, 3), 256, 0, stream>>>(phist, boff, rp_ho, rp_oh, rp_src);
  // merged: xcdg + scatter3, flat grid, type = bid%5 (co-resident)
  sxc_k<<<62500, 256, 0, stream>>>(xh_in, xo_in, xhb1, xob1, vbuf, aset0,
                                   ei_ho, ei_oh, ea_ho, ea_oh,
                                   rp_ho, rp_oh, rp_src, cur,
                                   rec_ho, rec_oh, eap_src);

  const unsigned short* xh = xhb1;
  const unsigned short* xo = xob1;
  unsigned short* xh_bufs[2] = {xhb0, xhb1};
  unsigned short* xo_bufs[2] = {xob0, xob1};
  float* asets[2] = {aset0, aset1};
  for (int l = 0; l < LAY; ++l){
    unsigned short* xo_n = xo_bufs[l & 1];
    unsigned short* xh_n = xh_bufs[l & 1];
    float* cur_a = asets[l & 1];
    float* nxt_a = asets[(l & 1) ^ 1];
    int doNext = (l < LAY-1);
    int ln = doNext ? (l+1) : l;   // valid vbuf index even when unused
    gesm_k<<<dim3(3, 391, 2), 256, 0, stream>>>(xh, xo,
                                                Wtb + (size_t)l*DIM*DIM,
                                                Wtb + (size_t)(LAY + l)*DIM*DIM,
                                                hSb0, hSb1, NNODE,
                                                rp_ho, rec_ho, rp_oh, rec_oh,
                                                cur_a, webuf + (size_t)l*4,
                                                lgsrc_ho, lgsrc_oh);
    attn2_k<<<dim3(12500, 2), 256, 0, stream>>>(rp_ho, lgsrc_ho,
                                                rp_oh, lgsrc_oh,
                                                nxt_a,
                                                hSb0, hSb1,
                                                bias_ho + (size_t)l*DIM, bias_oh + (size_t)l*DIM,
                                                xo, xh, xo_n, xh_n,
                                                vbuf + (size_t)ln*4*DIM,
                                                l > 0, doNext);
    xh = xh_n; xo = xo_n;
  }

  pool2_k<<<dim3(BB, 2), 256, 0, stream>>>(xh, xo, hbatch, obatch, hpool, opool);
  epool_k<<<BB, 256, 0, stream>>>(rp_src, hbatch, eap_src, W_emlp, b_emlp, epool);
  head_k<<<BB, 256, 0, stream>>>(hpool, opool, epool, W_p1, b_p1, W_p2, b_p2, out);
}

// Round 10
// 1411.021 us; speedup vs baseline: 1.0667x; 1.0250x over previous
//
#include <hip/hip_runtime.h>
#include <math.h>

// HELPv3: 8-layer bipartite GAT + pooling + 2 softmax heads.
// R17: (1) attn gather tail: masked 4-wide rounds (clamped idx, zero weight)
//          replace up-to-3 SERIAL dependent tail loads -> 1 parallel round.
//      (2) scanB: 3-wave shfl_up prefix scan (was 3-thread 49-iter serial
//          global-latency loop, ~10us).
//      (3) pool2+epool merged into one dispatch (grid (BB,3)).
// Carried: gesm (gemm BK=64 + elsm, one dispatch), sxc flat merge, normalized-
//          weight lgsrc, readlane gather, cvt_pk trims, 16B records, priv hist.

#define NNODE 50000
#define EDG   500000
#define DIM   256
#define LAY   8
#define BB    512
#define CC    117
#define EMBD  544
#define SCB   49          // scan blocks: 49*1024 >= 50000
#define HW    16384       // hist window (nodes), 64KB LDS
#define HC    16          // hist chunk count (private copies)
#define HNW   4           // windows: 4*16384 >= 50000
#define LDSE  4096        // elsm LDS logit slots (16KB, unioned with gemm LDS)

typedef short bf16x8 __attribute__((ext_vector_type(8)));
typedef float f32x4  __attribute__((ext_vector_type(4)));

static __device__ __forceinline__ float lrelu(float x){ return x >= 0.f ? x : 0.2f*x; }
static __device__ __forceinline__ unsigned short f2b(float f){
  unsigned int u = __float_as_uint(f);
  unsigned int r = (u + 0x7fffu + ((u >> 16) & 1u)) >> 16;   // RNE
  return (unsigned short)r;
}
static __device__ __forceinline__ float b2f(unsigned short u){
  return __uint_as_float(((unsigned int)u) << 16);
}
static __device__ __forceinline__ float blo(unsigned int u){
  return __uint_as_float(u << 16);
}
static __device__ __forceinline__ float bhi(unsigned int u){
  return __uint_as_float(u & 0xffff0000u);
}
// packed RNE f32->bf16x2 (same rounding as f2b, 1 instr instead of ~8)
static __device__ __forceinline__ unsigned cvtpk(float lo, float hi){
  unsigned r;
  asm("v_cvt_pk_bf16_f32 %0, %1, %2" : "=v"(r) : "v"(lo), "v"(hi));
  return r;
}
// wave-uniform broadcasts (SGPR result; no ds_bpermute)
static __device__ __forceinline__ float rdlane_f(float v, int id){
  return __uint_as_float(__builtin_amdgcn_readlane(__float_as_uint(v), id));
}
static __device__ __forceinline__ int rdlane_i(int v, int id){
  return __builtin_amdgcn_readlane(v, id);
}

static __device__ __forceinline__ void gload_lds16(const void* g, void* l){
  __builtin_amdgcn_global_load_lds((const __attribute__((address_space(1))) void*)g,
                                   (__attribute__((address_space(3))) void*)l,
                                   16, 0, 0);
}

// v[k] = sum_j W[k*256+j]*a[j] for 32 (l,rel,which) combos; one wave per output k
__global__ void vcompute_k(const float* __restrict__ Wsho, const float* __restrict__ Wdho,
                           const float* __restrict__ asho, const float* __restrict__ adho,
                           const float* __restrict__ Wsoh, const float* __restrict__ Wdoh,
                           const float* __restrict__ asoh, const float* __restrict__ adoh,
                           float* __restrict__ vbuf){
  int gid = blockIdx.x*blockDim.x + threadIdx.x;
  int wv = gid >> 6, lane = gid & 63;
  if (wv >= 32*DIM) return;
  int p = wv >> 8, k = wv & 255;
  int which = p & 1, rel = (p>>1)&1, l = p>>2;
  const float* W; const float* a;
  if (rel==0){ W = which? Wdho : Wsho; a = which? adho : asho; }
  else       { W = which? Wdoh : Wsoh; a = which? adoh : asoh; }
  W += (size_t)l*DIM*DIM; a += (size_t)l*DIM;
  const float4* w4 = (const float4*)(W + (size_t)k*DIM);
  const float4* a4 = (const float4*)a;
  float4 wv4 = w4[lane], av4 = a4[lane];
  float s = wv4.x*av4.x + wv4.y*av4.y + wv4.z*av4.z + wv4.w*av4.w;
  for (int off=32; off; off>>=1) s += __shfl_xor(s, off);
  if (lane==0) vbuf[(size_t)p*DIM + k] = s;
}

__global__ void wecompute_k(const float* __restrict__ Weho, const float* __restrict__ aeho,
                            const float* __restrict__ Weoh, const float* __restrict__ aeoh,
                            float* __restrict__ webuf){
  int blk = blockIdx.x;            // l*2 + rel
  int rel = blk & 1, l = blk >> 1;
  const float* We = rel? Weoh : Weho;
  const float* ae = rel? aeoh : aeho;
  int lane = threadIdx.x;          // 64
  const float4* w0 = (const float4*)(We + (size_t)l*2*DIM);
  const float4* w1 = (const float4*)(We + (size_t)l*2*DIM + DIM);
  const float4* a4 = (const float4*)(ae + (size_t)l*DIM);
  float4 av = a4[lane], x0 = w0[lane], x1 = w1[lane];
  float s0 = x0.x*av.x + x0.y*av.y + x0.z*av.z + x0.w*av.w;
  float s1 = x1.x*av.x + x1.y*av.y + x1.z*av.z + x1.w*av.w;
  for (int off=32; off; off>>=1){ s0 += __shfl_xor(s0, off); s1 += __shfl_xor(s1, off); }
  if (lane==0){ webuf[blk*2] = s0; webuf[blk*2+1] = s1; }
}

// privatized histogram: block (x=chunk, y=window, z=array) counts its chunk's
// in-window keys in LDS, writes private copy (coalesced, no atomics).
// phist[((z*HNW + y)*HC + x)*HW + off]
__global__ void histp_k(const int* __restrict__ ei_ho, const int* __restrict__ ei_oh,
                        int* __restrict__ phist){
  __shared__ int h[HW];
  int x = blockIdx.x, y = blockIdx.y, z = blockIdx.z, t = threadIdx.x;
  for (int i=t; i<HW; i+=256) h[i] = 0;
  __syncthreads();
  const int* keys = (z==0)? (ei_ho + EDG) : (z==1)? (ei_oh + EDG) : ei_ho;
  int lo = y << 14;
  int e0 = x * (EDG/HC), e1 = e0 + (EDG/HC);
  for (int e = e0 + t; e < e1; e += 256){
    int k = keys[e] - lo;
    if ((unsigned)k < (unsigned)HW) atomicAdd(&h[k], 1);
  }
  __syncthreads();
  int* dst = phist + (size_t)(((z*HNW + y)*HC + x))*HW;
  for (int i=t; i<HW; i+=256) dst[i] = h[i];
}

static __device__ __forceinline__ int4 phist_sum4(const int* __restrict__ phist,
                                                  int z, int idx){
  int win = idx >> 14, off = idx & (HW-1);
  const int* base = phist + (size_t)((z*HNW + win)*HC)*HW + off;
  int4 s = make_int4(0,0,0,0);
  #pragma unroll
  for (int c=0;c<HC;c++){
    int4 v = *(const int4*)(base + (size_t)c*HW);
    s.x += v.x; s.y += v.y; s.z += v.z; s.w += v.w;
  }
  return s;
}

// Phase A: per-block sums (grid SCB x 3, 256 thr, 4 elem/thr)
__global__ void scanA_k(const int* __restrict__ phist, int* __restrict__ bsum){
  __shared__ int sh[256];
  int y = blockIdx.y, b = blockIdx.x, t = threadIdx.x;
  int idx = b*1024 + t*4;
  int s = 0;
  if (idx + 3 < NNODE){
    int4 v = phist_sum4(phist, y, idx);
    s = v.x + v.y + v.z + v.w;
  } else {
    for (int j=0;j<4;j++) if (idx+j < NNODE){
      int win = (idx+j) >> 14, off = (idx+j) & (HW-1);
      for (int c=0;c<HC;c++) s += phist[(size_t)((y*HNW+win)*HC+c)*HW + off];
    }
  }
  sh[t] = s; __syncthreads();
  for (int off=128; off; off>>=1){ if (t<off) sh[t] += sh[t+off]; __syncthreads(); }
  if (t==0) bsum[y*SCB + b] = sh[0];
}

// 3 waves (one per array), shfl_up prefix scan over SCB=49 block sums
__global__ void scanB_k(const int* __restrict__ bsum, int* __restrict__ boff,
                        int* __restrict__ rp0, int* __restrict__ rp1, int* __restrict__ rp2){
  int t = threadIdx.x;
  int row = t >> 6, lane = t & 63;
  if (row >= 3) return;
  int v = (lane < SCB) ? bsum[row*SCB + lane] : 0;
  int s = v;
  for (int off=1; off<64; off<<=1){
    int u = __shfl_up(s, off);
    if (lane >= off) s += u;
  }
  if (lane < SCB) boff[row*SCB + lane] = s - v;   // exclusive
  int tot = __shfl(s, SCB-1);
  if (lane == 0){
    int* rp = (row==0)? rp0 : (row==1)? rp1 : rp2;
    rp[NNODE] = tot;
  }
}

__global__ void scanC_k(const int* __restrict__ phist, const int* __restrict__ boff,
                        int* __restrict__ rp0, int* __restrict__ rp1, int* __restrict__ rp2){
  __shared__ int sh[256];
  int y = blockIdx.y, b = blockIdx.x, t = threadIdx.x;
  int* rp = (y==0)? rp0 : (y==1)? rp1 : rp2;
  int idx = b*1024 + t*4;
  int c[4] = {0,0,0,0};
  if (idx + 3 < NNODE){
    int4 v = phist_sum4(phist, y, idx);
    c[0]=v.x; c[1]=v.y; c[2]=v.z; c[3]=v.w;
  } else {
    for (int j=0;j<4;j++) if (idx+j < NNODE){
      int win = (idx+j) >> 14, off = (idx+j) & (HW-1);
      for (int cc=0;cc<HC;cc++) c[j] += phist[(size_t)((y*HNW+win)*HC+cc)*HW + off];
    }
  }
  int mysum = c[0]+c[1]+c[2]+c[3];
  sh[t] = mysum; __syncthreads();
  for (int off=1; off<256; off<<=1){
    int v = (t>=off) ? sh[t-off] : 0;
    __syncthreads();
    sh[t] += v;
    __syncthreads();
  }
  int base = boff[y*SCB + b] + (sh[t] - mysum);
  int run = 0;
  for (int j=0;j<4;j++){
    if (idx+j < NNODE) rp[idx+j] = base + run;
    run += c[j];
  }
}

// merged xcdg + scatter3, FLAT 1-D grid, work type = bid%5.
// type<2: fp32->bf16 convert + layer-0 a_s/a_d dots (one wave per row, z=type).
// type>=2: scatter y=2 dst(ho), y=3 dst(oh), y=4 src(ho); 16B records
// {src_as_float, ea.x, ea.y, dst_as_float} -> 1 dirty line/edge.
__global__ void sxc_k(const float* __restrict__ xh_in, const float* __restrict__ xo_in,
                      unsigned short* __restrict__ xhb, unsigned short* __restrict__ xob,
                      const float* __restrict__ vbuf, float* __restrict__ aset,
                      const int* __restrict__ ei_ho, const int* __restrict__ ei_oh,
                      const float* __restrict__ ea_ho, const float* __restrict__ ea_oh,
                      const int* __restrict__ rp0, const int* __restrict__ rp1,
                      const int* __restrict__ rp2, int* __restrict__ cur,
                      float4* __restrict__ rec0, float4* __restrict__ rec1,
                      float2* __restrict__ eap2){
  int bid = blockIdx.x;
  int y = bid % 5, x = bid / 5;
  if (y < 2){
    int gid = x*blockDim.x + threadIdx.x;
    int w = gid >> 6, lane = gid & 63;
    if (w >= NNODE) return;
    int z = y;
    const float* X = z? xo_in : xh_in;
    unsigned short* O = z? xob : xhb;
    const float* v1 = vbuf + (size_t)(z? 2:0)*DIM;   // as (src-role)
    const float* v2 = vbuf + (size_t)(z? 1:3)*DIM;   // ad (dst-role)
    float* o1 = aset + (size_t)(z? 2:0)*NNODE;
    float* o2 = aset + (size_t)(z? 1:3)*NNODE;
    float4 xv = ((const float4*)(X + (size_t)w*DIM))[lane];
    uint2 ob; ob.x = cvtpk(xv.x, xv.y); ob.y = cvtpk(xv.z, xv.w);
    ((uint2*)O)[(size_t)w*64 + lane] = ob;
    float4 a = ((const float4*)v1)[lane];
    float4 b = ((const float4*)v2)[lane];
    float s1 = xv.x*a.x + xv.y*a.y + xv.z*a.z + xv.w*a.w;
    float s2 = xv.x*b.x + xv.y*b.y + xv.z*b.z + xv.w*b.w;
    for (int off=32; off; off>>=1){ s1 += __shfl_xor(s1, off); s2 += __shfl_xor(s2, off); }
    if (lane==0){ o1[w] = s1; o2[w] = s2; }
  } else {
    int e = x*blockDim.x + threadIdx.x;
    if (e >= EDG) return;
    int yy = y - 2;
    if (yy == 0){
      int d = ei_ho[EDG + e];
      int pos = rp0[d] + atomicAdd(&cur[d], 1);
      rec0[pos] = make_float4(__int_as_float(ei_ho[e]), ea_ho[2*e], ea_ho[2*e+1],
                              __int_as_float(d));
    } else if (yy == 1){
      int d = ei_oh[EDG + e];
      int pos = rp1[d] + atomicAdd(&cur[NNODE + d], 1);
      rec1[pos] = make_float4(__int_as_float(ei_oh[e]), ea_oh[2*e], ea_oh[2*e+1],
                              __int_as_float(d));
    } else {
      int s = ei_ho[e];
      int pos = rp2[s] + atomicAdd(&cur[2*NNODE + s], 1);
      eap2[pos] = make_float2(ea_ho[2*e], ea_ho[2*e+1]);
    }
  }
}

// Wt[rel][l][n][k] = bf16(W[rel][l][k][n])
__global__ void wtconv_k(const float* __restrict__ Who, const float* __restrict__ Woh,
                         unsigned short* __restrict__ Wt){
  int gid = blockIdx.x*blockDim.x + threadIdx.x;   // < 1048576
  int rel = gid >> 19;
  int rem = gid & ((1<<19)-1);
  int l = rem >> 16;
  int idx = rem & 65535;
  int n = idx >> 8, k = idx & 255;
  const float* W = rel ? Woh : Who;
  Wt[gid] = f2b(W[(size_t)l*65536 + (size_t)k*256 + n]);
}

// merged GEMM pair + elsm. Role on blockIdx.x (fastest).
// role 0/1: H = x @ Wl, 128x128 tile, BK=64 (8 barriers/block, 32 MFMA/phase).
//   LDS chunk c (0..1023): row=((c>>7)<<4)|(c&15), sq=(c>>4)&7 (bijection).
// role 2: elsm; rel = blockIdx.z, 128 nodes per blockIdx.y: edge logits ->
//   lgsrc {lg,src}; per-node m,sum; REWRITE lgsrc.x with normalized weight.
__global__ __launch_bounds__(256) void gesm_k(
    const unsigned short* __restrict__ A0, const unsigned short* __restrict__ A1,
    const unsigned short* __restrict__ B0, const unsigned short* __restrict__ B1,
    unsigned short* __restrict__ H0, unsigned short* __restrict__ H1, int M,
    const int* __restrict__ rp0, const float4* __restrict__ rec0,
    const int* __restrict__ rp1, const float4* __restrict__ rec1,
    const float* __restrict__ cur_a, const float* __restrict__ wepl,
    uint2* __restrict__ lgsrc0, uint2* __restrict__ lgsrc1){
  union SMu {
    struct { unsigned short As[8192]; unsigned short Bs[8192]; } g;  // 32KB
    float lgs[LDSE];                                                 // 16KB
  };
  __shared__ __align__(16) SMu sh;

  int role = blockIdx.x;
  if (role < 2){
    int z = role;
    const unsigned short* A  = z? A1 : A0;
    const unsigned short* Bt = z? B1 : B0;
    unsigned short* H        = z? H1 : H0;
    int tid = threadIdx.x;
    int col0 = blockIdx.z * 128;
    int row0 = blockIdx.y * 128;
    int w = tid >> 6, lane = tid & 63;
    int q = lane >> 4, ml = lane & 15;
    f32x4 acc[2][8];
    #pragma unroll
    for (int i=0;i<2;i++)
      #pragma unroll
      for (int j=0;j<8;j++) acc[i][j] = (f32x4){0.f,0.f,0.f,0.f};

    // per-lane permuted global sources, 4 staging issues (1024 chunks of 16B)
    const unsigned short* srcA[4];
    const unsigned short* srcB[4];
    #pragma unroll
    for (int p=0;p<4;p++){
      int c = p*256 + w*64 + lane;             // linear chunk index in LDS
      int row = ((c>>7)<<4) | (c&15);
      int sq  = (c>>4)&7;
      int gr = row0 + row; if (gr >= M) gr = M-1;   // clamp; masked at store
      srcA[p] = A  + (size_t)gr*256 + sq*8;
      srcB[p] = Bt + (size_t)(col0 + row)*256 + sq*8;
    }

    for (int k0 = 0; k0 < 256; k0 += 64){
      #pragma unroll
      for (int p = 0; p < 4; ++p){
        gload_lds16(srcA[p], &sh.g.As[(size_t)(p*256 + w*64)*8]);
        gload_lds16(srcB[p], &sh.g.Bs[(size_t)(p*256 + w*64)*8]);
        srcA[p] += 64; srcB[p] += 64;
      }
      __syncthreads();
      #pragma unroll
      for (int kk = 0; kk < 2; ++kk){
        bf16x8 a0 = *(const bf16x8*)&sh.g.As[((((2*w+0)*8) + kk*4 + q)*16 + ml)*8];
        bf16x8 a1 = *(const bf16x8*)&sh.g.As[((((2*w+1)*8) + kk*4 + q)*16 + ml)*8];
        #pragma unroll
        for (int nf = 0; nf < 8; ++nf){
          bf16x8 b = *(const bf16x8*)&sh.g.Bs[((nf*8 + kk*4 + q)*16 + ml)*8];
          acc[0][nf] = __builtin_amdgcn_mfma_f32_16x16x32_bf16(a0, b, acc[0][nf], 0,0,0);
          acc[1][nf] = __builtin_amdgcn_mfma_f32_16x16x32_bf16(a1, b, acc[1][nf], 0,0,0);
        }
      }
      __syncthreads();
    }
    #pragma unroll
    for (int mf = 0; mf < 2; ++mf){
      #pragma unroll
      for (int r = 0; r < 4; ++r){
        int gr = row0 + 32*w + 16*mf + q*4 + r;
        if (gr < M){
          #pragma unroll
          for (int nf = 0; nf < 8; ++nf)
            H[(size_t)gr*256 + col0 + nf*16 + ml] = f2b(acc[mf][nf][r]);
        }
      }
    }
  } else {
    int rel = blockIdx.z;
    const int* rp = rel? rp1 : rp0;
    const float4* rec = rel? rec1 : rec0;
    const float* a_s = cur_a + (size_t)(rel? 2:0)*NNODE;
    const float* a_d = cur_a + (size_t)(rel? 3:1)*NNODE;
    float w0 = wepl[rel? 2:0], w1 = wepl[rel? 3:1];
    uint2* lgsrc = rel? lgsrc1 : lgsrc0;
    int n0 = blockIdx.y * 128;
    int n1 = n0 + 128; if (n1 > NNODE) n1 = NNODE;
    int t = threadIdx.x;
    int e0 = rp[n0], e1 = rp[n1];
    bool fit = (e1 - e0) <= LDSE;
    for (int e = e0 + t; e < e1; e += 256){
      float4 r = rec[e];
      int src = __float_as_int(r.x);
      int dst = __float_as_int(r.w);
      float lg = lrelu(a_s[src] + a_d[dst] + r.y*w0 + r.z*w1);
      lgsrc[e] = make_uint2(__float_as_uint(lg), (unsigned)src);
      if (fit) sh.lgs[e - e0] = lg;
    }
    __syncthreads();
    if (t < 128){
      int n = n0 + t;
      if (n < NNODE){
        int st = rp[n], en = rp[n+1];
        float m = -INFINITY, s = 0.f;
        if (fit){
          for (int p=st;p<en;p++) m = fmaxf(m, sh.lgs[p-e0]);
          for (int p=st;p<en;p++) s += __expf(sh.lgs[p-e0] - m);
          float inv = __builtin_amdgcn_rcpf(s);
          for (int p=st;p<en;p++)
            lgsrc[p].x = __float_as_uint(__expf(sh.lgs[p-e0] - m) * inv);
        } else {
          for (int p=st;p<en;p++) m = fmaxf(m, __uint_as_float(lgsrc[p].x));
          for (int p=st;p<en;p++) s += __expf(__uint_as_float(lgsrc[p].x) - m);
          float inv = __builtin_amdgcn_rcpf(s);
          for (int p=st;p<en;p++)
            lgsrc[p].x = __float_as_uint(__expf(__uint_as_float(lgsrc[p].x) - m) * inv);
        }
      }
    }
  }
}

// fused attn pair (y = relation). One wave per dst node. Pure gather:
// lgsrc.x holds the normalized weight. Main loop 8-wide; tail = masked 4-wide
// rounds (clamped row idx, zero weight) -- no serial dependent tail loads.
__global__ void attn2_k(const int* __restrict__ rp0, const uint2* __restrict__ lgsrc0,
                        const int* __restrict__ rp1, const uint2* __restrict__ lgsrc1,
                        float* __restrict__ nxt_a,
                        const unsigned short* __restrict__ hs0,
                        const unsigned short* __restrict__ hs1,
                        const float* __restrict__ bias0, const float* __restrict__ bias1,
                        const unsigned short* __restrict__ xprev0,
                        const unsigned short* __restrict__ xprev1,
                        unsigned short* __restrict__ xnext0,
                        unsigned short* __restrict__ xnext1,
                        const float* __restrict__ vbl,
                        int hasRes, int doNext){
  int gid = blockIdx.x*blockDim.x + threadIdx.x;
  int w = gid >> 6, lane = gid & 63;
  if (w >= NNODE) return;
  int rel = blockIdx.y;
  const int* rowptr = rel? rp1 : rp0;
  const uint2* lgsrc = rel? lgsrc1 : lgsrc0;
  const unsigned short* hs = rel? hs1 : hs0;
  const float* bias = rel? bias1 : bias0;
  const unsigned short* xprev = rel? xprev1 : xprev0;
  unsigned short* xnext = rel? xnext1 : xnext0;

  int st = rowptr[w], en = rowptr[w+1];
  int deg = en - st;

  // hoisted independent epilogue loads (overlap their latency with the gather)
  float4 bv = ((const float4*)bias)[lane];
  uint2 rres = ((const uint2*)xprev)[(size_t)w*64 + lane];
  float4 va = ((const float4*)(vbl + (size_t)(rel? 0:2)*DIM))[lane];
  float4 vc = ((const float4*)(vbl + (size_t)(rel? 3:1)*DIM))[lane];

  float ax=0.f, ay=0.f, az=0.f, aw=0.f;
  if (deg > 0 && deg <= 64){
    int sreg = 0; float wgt = 0.f;
    if (lane < deg){
      uint2 ls = lgsrc[st + lane];
      sreg = (int)ls.y;
      wgt = __uint_as_float(ls.x);
    }
    int i = 0;
    for (; i + 7 < deg; i += 8){
      float wi[8]; const uint2* rp[8];
      #pragma unroll
      for (int j=0;j<8;j++){
        wi[j] = rdlane_f(wgt, i+j);
        rp[j] = (const uint2*)(hs + (size_t)rdlane_i(sreg, i+j)*DIM);
      }
      uint2 hv[8];
      #pragma unroll
      for (int j=0;j<8;j++) hv[j] = rp[j][lane];
      #pragma unroll
      for (int j=0;j<8;j++){
        ax += wi[j]*blo(hv[j].x); ay += wi[j]*bhi(hv[j].x);
        az += wi[j]*blo(hv[j].y); aw += wi[j]*bhi(hv[j].y);
      }
    }
    for (; i < deg; i += 4){            // masked 4-wide rounds, all parallel
      float wi[4]; const uint2* rp[4];
      #pragma unroll
      for (int j=0;j<4;j++){
        int id = i + j;
        int ok = (id < deg);
        if (!ok) id = deg - 1;
        wi[j] = ok ? rdlane_f(wgt, id) : 0.f;
        rp[j] = (const uint2*)(hs + (size_t)rdlane_i(sreg, id)*DIM);
      }
      uint2 hv[4];
      #pragma unroll
      for (int j=0;j<4;j++) hv[j] = rp[j][lane];
      #pragma unroll
      for (int j=0;j<4;j++){
        ax += wi[j]*blo(hv[j].x); ay += wi[j]*bhi(hv[j].x);
        az += wi[j]*blo(hv[j].y); aw += wi[j]*bhi(hv[j].y);
      }
    }
  } else if (deg > 64){
    for (int p = st; p < en; ++p){
      uint2 ls = lgsrc[p];
      float wgt = __uint_as_float(ls.x);
      const uint2* rp = (const uint2*)(hs + (size_t)ls.y*DIM);
      uint2 hv = rp[lane];
      ax += wgt*blo(hv.x); ay += wgt*bhi(hv.x);
      az += wgt*blo(hv.y); aw += wgt*bhi(hv.y);
    }
  }

  float resw = hasRes ? 1.f : 0.f;
  float4 o;
  o.x = fmaxf(ax + bv.x, 0.f) + resw*blo(rres.x);
  o.y = fmaxf(ay + bv.y, 0.f) + resw*bhi(rres.x);
  o.z = fmaxf(az + bv.z, 0.f) + resw*blo(rres.y);
  o.w = fmaxf(aw + bv.w, 0.f) + resw*bhi(rres.y);
  uint2 ob; ob.x = cvtpk(o.x, o.y); ob.y = cvtpk(o.z, o.w);
  ((uint2*)xnext)[(size_t)w*64 + lane] = ob;
  if (doNext){
    float s1 = o.x*va.x + o.y*va.y + o.z*va.z + o.w*va.w;
    float s2 = o.x*vc.x + o.y*vc.y + o.z*vc.z + o.w*vc.w;
    for (int off=32; off; off>>=1){ s1 += __shfl_xor(s1, off); s2 += __shfl_xor(s2, off); }
    if (lane==0){
      float* asn = nxt_a + (size_t)(rel? 0:2)*NNODE;
      float* adn = nxt_a + (size_t)(rel? 3:1)*NNODE;
      asn[w] = s1; adn[w] = s2;
    }
  }
}

__device__ __forceinline__ int lowerb(const int* a, int n, int v){
  int lo=0, hi=n;
  while (lo < hi){ int m = (lo+hi)>>1; if (a[m] < v) lo = m+1; else hi = m; }
  return lo;
}

// merged pooling: y=0 pool-h, y=1 pool-o (coalesced column sums),
// y=2 edge-MLP pool (CSR-grouped edges, register accumulation).
__global__ void poolep_k(const unsigned short* __restrict__ xh, const unsigned short* __restrict__ xo,
                         const int* __restrict__ hbatch, const int* __restrict__ obatch,
                         float* __restrict__ hpool, float* __restrict__ opool,
                         const int* __restrict__ rp_src, const float2* __restrict__ eaperm,
                         const float* __restrict__ Wem, const float* __restrict__ bem,
                         float* __restrict__ epool){
  __shared__ float ps[8][33];
  int y = blockIdx.y;
  int b = blockIdx.x, t = threadIdx.x; // 256
  if (y < 2){
    const unsigned short* x = y? xo : xh;
    const int* batch = y? obatch : hbatch;
    float* out = y? opool : hpool;
    int st = lowerb(batch, NNODE, b), en = lowerb(batch, NNODE, b+1);
    float s = 0.f;
    for (int i=st;i<en;i++) s += b2f(x[(size_t)i*DIM + t]);
    out[(size_t)b*DIM + t] = s / fmaxf((float)(en - st), 1.f);
  } else {
    int j = t & 31, g = t >> 5;
    int nst = lowerb(hbatch, NNODE, b), nen = lowerb(hbatch, NNODE, b+1);
    int est = rp_src[nst], een = rp_src[nen];
    float w0 = Wem[j], w1 = Wem[32+j], bb = bem[j];
    float s = 0.f;
    for (int p = est + g; p < een; p += 8){
      float2 e = eaperm[p];
      s += fmaxf(e.x*w0 + e.y*w1 + bb, 0.f);
    }
    ps[g][j] = s; __syncthreads();
    if (g == 0){
      float tot = 0.f;
      #pragma unroll
      for (int gg=0; gg<8; gg++) tot += ps[gg][j];
      epool[(size_t)b*32 + j] = tot / fmaxf((float)(een - est), 1.f);
    }
  }
}

__global__ void head_k(const float* __restrict__ hpool, const float* __restrict__ opool,
                       const float* __restrict__ epool,
                       const float* __restrict__ Wp1, const float* __restrict__ bp1,
                       const float* __restrict__ Wp2, const float* __restrict__ bp2,
                       float* __restrict__ out){
  __shared__ float emb[EMBD];
  __shared__ float red[256];
  int b = blockIdx.x, t = threadIdx.x; // 256
  emb[t] = hpool[(size_t)b*DIM + t];
  emb[DIM + t] = opool[(size_t)b*DIM + t];
  if (t < 32) emb[2*DIM + t] = epool[(size_t)b*32 + t];
  __syncthreads();
  for (int h = 0; h < 2; ++h){
    const float* Wp = h? Wp2 : Wp1;
    const float* bp = h? bp2 : bp1;
    float logit = -INFINITY;
    if (t < CC){
      float s = bp[t];
      for (int k=0;k<EMBD;k++) s += emb[k]*Wp[(size_t)k*CC + t];
      logit = s;
    }
    red[t] = logit; __syncthreads();
    for (int off=128; off; off>>=1){ if (t<off) red[t] = fmaxf(red[t], red[t+off]); __syncthreads(); }
    float mx = red[0]; __syncthreads();
    float ex = (t < CC) ? expf(logit - mx) : 0.f;
    red[t] = ex; __syncthreads();
    for (int off=128; off; off>>=1){ if (t<off) red[t] += red[t+off]; __syncthreads(); }
    float sm = red[0]; __syncthreads();
    if (t < CC) out[((size_t)b*2 + h)*CC + t] = ex / sm;
  }
}

extern "C" void kernel_launch(void* const* d_in, const int* in_sizes, int n_in,
                              void* d_out, int out_size, void* d_ws, size_t ws_size,
                              hipStream_t stream) {
  (void)in_sizes; (void)n_in; (void)out_size; (void)ws_size;
  const float* xh_in   = (const float*)d_in[0];
  const float* xo_in   = (const float*)d_in[1];
  const int*   ei_ho   = (const int*)d_in[2];
  const int*   ei_oh   = (const int*)d_in[3];
  const float* ea_ho   = (const float*)d_in[4];
  const float* ea_oh   = (const float*)d_in[5];
  const int*   hbatch  = (const int*)d_in[6];
  const int*   obatch  = (const int*)d_in[7];
  const float* Wsrc_ho = (const float*)d_in[8];
  const float* Wdst_ho = (const float*)d_in[9];
  const float* asrc_ho = (const float*)d_in[10];
  const float* adst_ho = (const float*)d_in[11];
  const float* Wedge_ho= (const float*)d_in[12];
  const float* aedge_ho= (const float*)d_in[13];
  const float* bias_ho = (const float*)d_in[14];
  const float* Wsrc_oh = (const float*)d_in[15];
  const float* Wdst_oh = (const float*)d_in[16];
  const float* asrc_oh = (const float*)d_in[17];
  const float* adst_oh = (const float*)d_in[18];
  const float* Wedge_oh= (const float*)d_in[19];
  const float* aedge_oh= (const float*)d_in[20];
  const float* bias_oh = (const float*)d_in[21];
  const float* W_emlp  = (const float*)d_in[22];
  const float* b_emlp  = (const float*)d_in[23];
  const float* W_p1    = (const float*)d_in[24];
  const float* b_p1    = (const float*)d_in[25];
  const float* W_p2    = (const float*)d_in[26];
  const float* b_p2    = (const float*)d_in[27];
  float* out = (float*)d_out;

  size_t ND = (size_t)NNODE*DIM;
  float* f = (float*)d_ws;
  float* aset0 = f;                        // [asho adho asoh adoh] set 0
  float* aset1 = aset0 + 4*NNODE;          // set 1
  float* vbuf  = aset1 + 4*NNODE;          // 32*256
  float* webuf = vbuf + 32*DIM;            // 32
  float* hpool = webuf + 32;               // BB*DIM
  float* opool = hpool + (size_t)BB*DIM;
  float* epool = opool + (size_t)BB*DIM;   // BB*32
  float4* rec_ho  = (float4*)(epool + (size_t)BB*32);   // E float4 records
  float4* rec_oh  = rec_ho + EDG;
  float2* eap_src = (float2*)(rec_oh + EDG);            // E float2
  unsigned short* xhb0 = (unsigned short*)(eap_src + EDG);  // 6 x ND bf16
  unsigned short* xhb1 = xhb0 + ND;        // also holds bf16(xh_in) initially
  unsigned short* xob0 = xhb1 + ND;
  unsigned short* xob1 = xob0 + ND;        // also holds bf16(xo_in) initially
  unsigned short* hSb0 = xob1 + ND;
  unsigned short* hSb1 = hSb0 + ND;
  unsigned short* Wtb  = hSb1 + ND;        // 2*8*65536 bf16
  int* cur     = (int*)(Wtb + (size_t)2*LAY*DIM*DIM);   // 3*NNODE cursors
  int* rp_ho   = cur + 3*NNODE;
  int* rp_oh   = rp_ho + NNODE + 1;
  int* rp_src  = rp_oh + NNODE + 1;
  int* bsum    = rp_src + NNODE + 1;       // 3*SCB
  int* boff    = bsum + 3*SCB;             // 3*SCB
  int* phist   = boff + 3*SCB;             // 3*HNW*HC*HW ints (~12.6MB)
  // overlay on phist after scanC (dead): per-layer weight/src buffers
  uint2*  lgsrc_ho = (uint2*)phist;                 // E uint2 (4MB)
  uint2*  lgsrc_oh = lgsrc_ho + EDG;                // E uint2 (4MB, total 8MB <= 12.58MB)

  hipMemsetAsync(cur, 0, sizeof(int)*3*NNODE, stream);
  vcompute_k<<<2048, 256, 0, stream>>>(Wsrc_ho, Wdst_ho, asrc_ho, adst_ho,
                                       Wsrc_oh, Wdst_oh, asrc_oh, adst_oh, vbuf);
  wecompute_k<<<16, 64, 0, stream>>>(Wedge_ho, aedge_ho, Wedge_oh, aedge_oh, webuf);
  wtconv_k<<<4096, 256, 0, stream>>>(Wsrc_ho, Wsrc_oh, Wtb);
  histp_k<<<dim3(HC, HNW, 3), 256, 0, stream>>>(ei_ho, ei_oh, phist);
  scanA_k<<<dim3(SCB, 3), 256, 0, stream>>>(phist, bsum);
  scanB_k<<<1, 192, 0, stream>>>(bsum, boff, rp_ho, rp_oh, rp_src);
  scanC_k<<<dim3(SCB, 3), 256, 0, stream>>>(phist, boff, rp_ho, rp_oh, rp_src);
  // merged: xcdg + scatter3, flat grid, type = bid%5 (co-resident)
  sxc_k<<<62500, 256, 0, stream>>>(xh_in, xo_in, xhb1, xob1, vbuf, aset0,
                                   ei_ho, ei_oh, ea_ho, ea_oh,
                                   rp_ho, rp_oh, rp_src, cur,
                                   rec_ho, rec_oh, eap_src);

  const unsigned short* xh = xhb1;
  const unsigned short* xo = xob1;
  unsigned short* xh_bufs[2] = {xhb0, xhb1};
  unsigned short* xo_bufs[2] = {xob0, xob1};
  float* asets[2] = {aset0, aset1};
  for (int l = 0; l < LAY; ++l){
    unsigned short* xo_n = xo_bufs[l & 1];
    unsigned short* xh_n = xh_bufs[l & 1];
    float* cur_a = asets[l & 1];
    float* nxt_a = asets[(l & 1) ^ 1];
    int doNext = (l < LAY-1);
    int ln = doNext ? (l+1) : l;   // valid vbuf index even when unused
    gesm_k<<<dim3(3, 391, 2), 256, 0, stream>>>(xh, xo,
                                                Wtb + (size_t)l*DIM*DIM,
                                                Wtb + (size_t)(LAY + l)*DIM*DIM,
                                                hSb0, hSb1, NNODE,
                                                rp_ho, rec_ho, rp_oh, rec_oh,
                                                cur_a, webuf + (size_t)l*4,
                                                lgsrc_ho, lgsrc_oh);
    attn2_k<<<dim3(12500, 2), 256, 0, stream>>>(rp_ho, lgsrc_ho,
                                                rp_oh, lgsrc_oh,
                                                nxt_a,
                                                hSb0, hSb1,
                                                bias_ho + (size_t)l*DIM, bias_oh + (size_t)l*DIM,
                                                xo, xh, xo_n, xh_n,
                                                vbuf + (size_t)ln*4*DIM,
                                                l > 0, doNext);
    xh = xh_n; xo = xo_n;
  }

  poolep_k<<<dim3(BB, 3), 256, 0, stream>>>(xh, xo, hbatch, obatch, hpool, opool,
                                            rp_src, eap_src, W_emlp, b_emlp, epool);
  head_k<<<BB, 256, 0, stream>>>(hpool, opool, epool, W_p1, b_p1, W_p2, b_p2, out);
}